// Round 13
// baseline (813.373 us; speedup 1.0000x reference)
//
#include <hip/hip_runtime.h>
#include <hip/hip_bf16.h>

// ---------------- constants ----------------
#define B_    16
#define SL_   512
#define S_    511
#define E_    256
#define NH_   4
#define I_    512
#define DHM_  128
#define DHS_  64
#define F_    384
#define NP_   8192               // padded row count (multiple of 64)
#define NROW  (B_*S_)            // 8176 real rows
#define EPS_  1e-5f

typedef __hip_bfloat16 bf16;
typedef unsigned short u16;
typedef __bf16 bf16x8v __attribute__((ext_vector_type(8)));
typedef float  f32x4v  __attribute__((ext_vector_type(4)));

__device__ __forceinline__ float rcp_(float x){ return __builtin_amdgcn_rcpf(x); }
__device__ __forceinline__ float sig_(float x){ return rcp_(1.f+__expf(-x)); }
__device__ __forceinline__ float silu_(float x){ return x*sig_(x); }
__device__ __forceinline__ float logsig_(float x){ return fminf(x,0.f) - __logf(1.f + __expf(-fabsf(x))); }
__device__ __forceinline__ float expneg_(float x){ return __expf(fminf(x,0.f)); }
__device__ __forceinline__ float expclamp_(float x){ return __expf(fminf(fmaxf(x,-80.f),80.f)); }
__device__ __forceinline__ float tanh_(float x){ return 1.f - 2.f*rcp_(__expf(2.f*x)+1.f); }

// ---------------- ONE-SHOT prep: all weight conversions in a single kernel ----------------
__global__ __launch_bounds__(256) void k_prep(
  const float* __restrict__ m_down_w, bf16* __restrict__ m_down_w16,
  const float* __restrict__ ffn_up_w, bf16* __restrict__ ffn_up_w16,
  const float* __restrict__ ffn_down_w, bf16* __restrict__ ffn_down_w16,
  const float* __restrict__ out_w1, bf16* __restrict__ out_w1_16,
  const float* __restrict__ out_w2, bf16* __restrict__ out_w2_16,
  const float* __restrict__ m_up_w, bf16* __restrict__ m_up_whi, bf16* __restrict__ m_up_wlo,
  const float* __restrict__ s_gate_w, float* __restrict__ gwT,
  const float* __restrict__ s_rec_w, bf16* __restrict__ wfrag)
{
  int i = blockIdx.x*256 + threadIdx.x;
  if (i < 131072){ m_down_w16[i] = __float2bfloat16(m_down_w[i]); return; }
  i -= 131072;
  if (i < 196608){              // ffn_up: dst row 2j+p = src row j + p*F
    int rp=i>>8, c=i&255; int j=rp>>1, p=rp&1;
    ffn_up_w16[i] = __float2bfloat16(ffn_up_w[(size_t)(j + p*F_)*E_ + c]); return;
  }
  i -= 196608;
  if (i < 98304){ ffn_down_w16[i] = __float2bfloat16(ffn_down_w[i]); return; }
  i -= 98304;
  if (i < 524288){ out_w1_16[i] = __float2bfloat16(out_w1[i]); return; }
  i -= 524288;
  if (i < 131072){ out_w2_16[i] = __float2bfloat16(out_w2[i]); return; }
  i -= 131072;
  if (i < 262144){
    float v = m_up_w[i];
    bf16 h = __float2bfloat16(v);
    m_up_whi[i]=h;
    m_up_wlo[i]=__float2bfloat16(v-__bfloat162float(h));
    return;
  }
  i -= 262144;
  if (i < 65536){               // gwT[blk][d][e] = s_gate_w[blk][e][d]
    int blk=i>>12, d=(i>>6)&63, e=i&63;
    gwT[(size_t)(blk*64+d)*64+e] = s_gate_w[(size_t)(blk*64+e)*64+d]; return;
  }
  i -= 65536;
  {                             // wfrag (K-permuted MFMA B-frags of s_rec_w)
    int j=i&7, l=(i>>3)&63, kf=(i>>9)&1, t=(i>>10)&15, n=i>>14;
    int g=t>>2;
    int e=(t&3)*16 + (l&15);
    int d=(l>>4)*16 + kf*8 + j;
    wfrag[i] = __float2bfloat16(s_rec_w[((size_t)((g*4+n)*64 + d))*64 + e]);
  }
}

// ---------------- embedding gather + fused LN0 -> split bf16 (shfl reductions) ----------------
__global__ __launch_bounds__(256) void k_embed(
  const int* __restrict__ questions, const int* __restrict__ responses, const int* __restrict__ skills,
  const float* __restrict__ q_embed, const float* __restrict__ qa_embed,
  const float* __restrict__ q_embed_diff, const float* __restrict__ qa_embed_diff,
  const float* __restrict__ difficult_param, const float* __restrict__ ln0w,
  float* __restrict__ x, float* __restrict__ qe,
  bf16* __restrict__ h_hi, bf16* __restrict__ h_lo,
  float* __restrict__ pide, int* __restrict__ tgt, int* __restrict__ qsh)
{
  __shared__ float pA[4], pB[4];
  int r = blockIdx.x; int e = threadIdx.x;
  float xa = 0.f;
  if (r < NROW){
    int b = r / S_, s = r % S_;
    int pid  = questions[b*SL_+s];
    int qd   = skills[b*SL_+s];
    int resp = responses[b*SL_+s];
    int t    = (resp > -1) ? resp : 0;
    float pe = difficult_param[pid];
    float q0 = q_embed[qd*E_+e];
    xa = q0 + qa_embed[t*E_+e] + pe*qa_embed_diff[t*E_+e];
    float qn = q0 + pe*q_embed_diff[qd*E_+e];
    x[(size_t)r*E_+e]=xa; qe[(size_t)r*E_+e]=qn;
    if (e==0){ pide[r]=pe; tgt[r]=t; qsh[r]=skills[b*SL_+s+1]; }
  } else {
    x[(size_t)r*E_+e]=0.f; qe[(size_t)r*E_+e]=0.f;
    if (e==0){ pide[r]=0.f; tgt[r]=-7; qsh[r]=0; }
  }
  float s_ = xa;
  for(int m=32;m;m>>=1) s_ += __shfl_xor(s_,m,64);
  if((e&63)==0) pA[e>>6]=s_;
  __syncthreads();
  float mu = (pA[0]+pA[1]+pA[2]+pA[3])*(1.f/E_);
  float d = xa-mu;
  float q_ = d*d;
  for(int m=32;m;m>>=1) q_ += __shfl_xor(q_,m,64);
  if((e&63)==0) pB[e>>6]=q_;
  __syncthreads();
  float var = (pB[0]+pB[1]+pB[2]+pB[3])*(1.f/E_);
  float o = d*rsqrtf(var+EPS_)*ln0w[e];
  bf16 hv = __float2bfloat16(o);
  h_hi[(size_t)r*E_+e] = hv;
  h_lo[(size_t)r*E_+e] = __float2bfloat16(o-__bfloat162float(hv));
}

// ---------------- split-bf16 MFMA GEMM: C = (Ah+Al)(Bh+Bl)^T + bias (drop lo*lo) ----------------
__global__ __launch_bounds__(256) void k_gemm16s(
  const bf16* __restrict__ Ah, const bf16* __restrict__ Al,
  const bf16* __restrict__ Bh, const bf16* __restrict__ Bl,
  const float* __restrict__ bias, float* __restrict__ C, int M, int K)
{
  int tid=threadIdx.x;
  int wave=tid>>6, lane=tid&63;
  int wr=wave>>1, wc=wave&1;
  int row0=blockIdx.y*64 + wr*32;
  int col0=blockIdx.x*64 + wc*32;
  int lrow = lane&15, lq = lane>>4;
  f32x4v acc[2][2] = {};
  size_t aoff = (size_t)(row0+lrow)*K + lq*8;
  size_t boff = (size_t)(col0+lrow)*K + lq*8;
  for(int k0=0;k0<K;k0+=32){
    bf16x8v ah0=*(const bf16x8v*)(Ah+aoff+k0), ah1=*(const bf16x8v*)(Ah+aoff+(size_t)16*K+k0);
    bf16x8v al0=*(const bf16x8v*)(Al+aoff+k0), al1=*(const bf16x8v*)(Al+aoff+(size_t)16*K+k0);
    bf16x8v bh0=*(const bf16x8v*)(Bh+boff+k0), bh1=*(const bf16x8v*)(Bh+boff+(size_t)16*K+k0);
    bf16x8v bl0=*(const bf16x8v*)(Bl+boff+k0), bl1=*(const bf16x8v*)(Bl+boff+(size_t)16*K+k0);
    acc[0][0]=__builtin_amdgcn_mfma_f32_16x16x32_bf16(ah0,bh0,acc[0][0],0,0,0);
    acc[0][1]=__builtin_amdgcn_mfma_f32_16x16x32_bf16(ah0,bh1,acc[0][1],0,0,0);
    acc[1][0]=__builtin_amdgcn_mfma_f32_16x16x32_bf16(ah1,bh0,acc[1][0],0,0,0);
    acc[1][1]=__builtin_amdgcn_mfma_f32_16x16x32_bf16(ah1,bh1,acc[1][1],0,0,0);
    acc[0][0]=__builtin_amdgcn_mfma_f32_16x16x32_bf16(ah0,bl0,acc[0][0],0,0,0);
    acc[0][1]=__builtin_amdgcn_mfma_f32_16x16x32_bf16(ah0,bl1,acc[0][1],0,0,0);
    acc[1][0]=__builtin_amdgcn_mfma_f32_16x16x32_bf16(ah1,bl0,acc[1][0],0,0,0);
    acc[1][1]=__builtin_amdgcn_mfma_f32_16x16x32_bf16(ah1,bl1,acc[1][1],0,0,0);
    acc[0][0]=__builtin_amdgcn_mfma_f32_16x16x32_bf16(al0,bh0,acc[0][0],0,0,0);
    acc[0][1]=__builtin_amdgcn_mfma_f32_16x16x32_bf16(al0,bh1,acc[0][1],0,0,0);
    acc[1][0]=__builtin_amdgcn_mfma_f32_16x16x32_bf16(al1,bh0,acc[1][0],0,0,0);
    acc[1][1]=__builtin_amdgcn_mfma_f32_16x16x32_bf16(al1,bh1,acc[1][1],0,0,0);
  }
  #pragma unroll
  for(int mi=0;mi<2;mi++){
    #pragma unroll
    for(int ni=0;ni<2;ni++){
      #pragma unroll
      for(int r=0;r<4;r++){
        int row=row0+mi*16+lq*4+r;
        int col=col0+ni*16+lrow;
        C[(size_t)row*M+col]=acc[mi][ni][r] + bias[col];
      }
    }
  }
}

// ---------------- bf16 MFMA GEMM (+ optional residual) ----------------
__global__ __launch_bounds__(256) void k_gemm16(
  const bf16* __restrict__ A, const bf16* __restrict__ Bw,
  const float* __restrict__ bias, const float* __restrict__ resid,
  float* __restrict__ C, bf16* __restrict__ C16,
  int M, int K, int relu)
{
  int tid=threadIdx.x;
  int wave=tid>>6, lane=tid&63;
  int wr=wave>>1, wc=wave&1;
  int row0=blockIdx.y*64 + wr*32;
  int col0=blockIdx.x*64 + wc*32;
  int lrow = lane&15, lq = lane>>4;
  f32x4v acc[2][2] = {};
  const bf16* Abase = A  + (size_t)(row0+lrow)*K + lq*8;
  const bf16* Bbase = Bw + (size_t)(col0+lrow)*K + lq*8;
  for(int k0=0;k0<K;k0+=32){
    bf16x8v a0 = *(const bf16x8v*)(Abase + k0);
    bf16x8v a1 = *(const bf16x8v*)(Abase + (size_t)16*K + k0);
    bf16x8v b0 = *(const bf16x8v*)(Bbase + k0);
    bf16x8v b1 = *(const bf16x8v*)(Bbase + (size_t)16*K + k0);
    acc[0][0]=__builtin_amdgcn_mfma_f32_16x16x32_bf16(a0,b0,acc[0][0],0,0,0);
    acc[0][1]=__builtin_amdgcn_mfma_f32_16x16x32_bf16(a0,b1,acc[0][1],0,0,0);
    acc[1][0]=__builtin_amdgcn_mfma_f32_16x16x32_bf16(a1,b0,acc[1][0],0,0,0);
    acc[1][1]=__builtin_amdgcn_mfma_f32_16x16x32_bf16(a1,b1,acc[1][1],0,0,0);
  }
  #pragma unroll
  for(int mi=0;mi<2;mi++){
    #pragma unroll
    for(int ni=0;ni<2;ni++){
      #pragma unroll
      for(int r=0;r<4;r++){
        int row=row0+mi*16+lq*4+r;       // C/D: col=lane&15, row=(lane>>4)*4+reg  [m89]
        int col=col0+ni*16+lrow;
        float v=acc[mi][ni][r] + (bias? bias[col]:0.f);
        if(relu) v=fmaxf(v,0.f);
        if(resid) v += resid[(size_t)row*M+col];
        if(C)   C[(size_t)row*M+col]=v;
        if(C16) C16[(size_t)row*M+col]=__float2bfloat16(v);
      }
    }
  }
}

// ---------------- fused ffn-up GEMM + relu(gate)*up -> bf16 ----------------
__global__ __launch_bounds__(256) void k_gemm16f(
  const bf16* __restrict__ A, const bf16* __restrict__ Bw,
  const float* __restrict__ bias, bf16* __restrict__ out, int K)
{
  int tid=threadIdx.x;
  int wave=tid>>6, lane=tid&63;
  int wr=wave>>1, wc=wave&1;
  int row0=blockIdx.y*64 + wr*32;
  int col0=blockIdx.x*64 + wc*32;
  int lrow = lane&15, lq = lane>>4;
  f32x4v acc[2][2] = {};
  const bf16* Abase = A  + (size_t)(row0+lrow)*K + lq*8;
  const bf16* Bbase = Bw + (size_t)(col0+lrow)*K + lq*8;
  for(int k0=0;k0<K;k0+=32){
    bf16x8v a0 = *(const bf16x8v*)(Abase + k0);
    bf16x8v a1 = *(const bf16x8v*)(Abase + (size_t)16*K + k0);
    bf16x8v b0 = *(const bf16x8v*)(Bbase + k0);
    bf16x8v b1 = *(const bf16x8v*)(Bbase + (size_t)16*K + k0);
    acc[0][0]=__builtin_amdgcn_mfma_f32_16x16x32_bf16(a0,b0,acc[0][0],0,0,0);
    acc[0][1]=__builtin_amdgcn_mfma_f32_16x16x32_bf16(a0,b1,acc[0][1],0,0,0);
    acc[1][0]=__builtin_amdgcn_mfma_f32_16x16x32_bf16(a1,b0,acc[1][0],0,0,0);
    acc[1][1]=__builtin_amdgcn_mfma_f32_16x16x32_bf16(a1,b1,acc[1][1],0,0,0);
  }
  #pragma unroll
  for(int mi=0;mi<2;mi++){
    #pragma unroll
    for(int ni=0;ni<2;ni++){
      #pragma unroll
      for(int r=0;r<4;r++){
        int row=row0+mi*16+lq*4+r;
        int col=col0+ni*16+lrow;
        float v=acc[mi][ni][r] + bias[(col>>1) + (col&1)*F_];
        float o = __shfl_xor(v, 1, 64);          // partner: same row, col^1
        if(!(lrow&1)){
          out[(size_t)row*F_ + (col>>1)] = __float2bfloat16(fmaxf(v,0.f)*o);
        }
      }
    }
  }
}

// ---------------- MEGA: conv(512)+silu -> headwise q,k,v (split bf16) -> ig/fg gates ------------
__global__ __launch_bounds__(256) void k_mega(
  const float* __restrict__ A,
  const float* __restrict__ cw, const float* __restrict__ cb,
  const float* __restrict__ wq, const float* __restrict__ wk, const float* __restrict__ wv,
  const float* __restrict__ wig, const float* __restrict__ big,
  const float* __restrict__ wfg, const float* __restrict__ bfg,
  float* __restrict__ xcout,
  bf16* __restrict__ qhi, bf16* __restrict__ qlo,
  bf16* __restrict__ khi, bf16* __restrict__ klo,
  bf16* __restrict__ vhi, bf16* __restrict__ vlo,
  float* __restrict__ igb, float* __restrict__ fgb)
{
  __shared__ float xcs[512];
  __shared__ float xms[512];
  __shared__ float qs[512], ks[512], vs[512];
  int r = blockIdx.x;
  int tid = threadIdx.x;
  if (r >= NROW){
    bf16 z = __float2bfloat16(0.f);
    size_t o = (size_t)r*512 + tid*2;
    qhi[o]=z; qhi[o+1]=z; qlo[o]=z; qlo[o+1]=z;
    khi[o]=z; khi[o+1]=z; klo[o]=z; klo[o+1]=z;
    vhi[o]=z; vhi[o+1]=z; vlo[o]=z; vlo[o+1]=z;
    return;
  }
  int b=r/S_, s=r%S_;
  const float* arow = A + (size_t)r*1024;
  for (int c=tid; c<512; c+=256){
    float acc = cb[c];
    #pragma unroll
    for(int j=0;j<4;j++){
      int ss=s-3+j;
      if(ss>=0) acc += cw[c*4+j]*A[((size_t)(b*S_+ss))*1024 + c];
    }
    acc = silu_(acc);
    xcs[c]=acc;
    xcout[(size_t)r*512+c]=acc;
    xms[c]=arow[c];
  }
  __syncthreads();
  for (int c=tid; c<512; c+=256){
    int n=c>>2, o=c&3;
    float aq=0.f, ak=0.f, av=0.f;
    #pragma unroll
    for(int d=0;d<4;d++){
      aq += xcs[n*4+d]*wq[(n*4+o)*4+d];
      ak += xcs[n*4+d]*wk[(n*4+o)*4+d];
      av += xms[n*4+d]*wv[(n*4+o)*4+d];
    }
    qs[c]=aq; ks[c]=ak; vs[c]=av;
    size_t oi=(size_t)r*512+c;
    bf16 qh=__float2bfloat16(aq); qhi[oi]=qh; qlo[oi]=__float2bfloat16(aq-__bfloat162float(qh));
    bf16 kh=__float2bfloat16(ak); khi[oi]=kh; klo[oi]=__float2bfloat16(ak-__bfloat162float(kh));
    bf16 vh=__float2bfloat16(av); vhi[oi]=vh; vlo[oi]=__float2bfloat16(av-__bfloat162float(vh));
  }
  __syncthreads();
  int h = tid>>6, lane = tid&63;
  float ai=0.f, af=0.f;
  for(int f=lane; f<1536; f+=64){
    float val = (f<512)? qs[f] : (f<1024)? ks[f-512] : vs[f-1024];
    ai += val*wig[h*1536+f];
    af += val*wfg[h*1536+f];
  }
  for(int m=32;m;m>>=1){ ai+=__shfl_xor(ai,m,64); af+=__shfl_xor(af,m,64); }
  if(lane==0){
    igb[(b*4+h)*512+s]=ai+big[h];
    fgb[(b*4+h)*512+s]=af+bfg[h];
  }
}

// ---------------- decay prep (parallel scans): one block per bh ----------------
__global__ __launch_bounds__(256) void k_decay(
  const float* __restrict__ igb, const float* __restrict__ fgb,
  float* __restrict__ cs1, float* __restrict__ g, float* __restrict__ M)
{
  int bh = blockIdx.x; int tid = threadIdx.x;
  __shared__ float buf[512];
  __shared__ float buf2[512];
  for (int s=tid; s<512; s+=256)
    buf[s] = (s<S_) ? logsig_(fgb[bh*512+s]) : 0.f;
  __syncthreads();
  for (int off=1; off<512; off<<=1){
    int s0=tid, s1=tid+256;
    float v0 = buf[s0] + ((s0>=off)? buf[s0-off] : 0.f);
    float v1 = buf[s1] + ((s1>=off)? buf[s1-off] : 0.f);
    __syncthreads();
    buf[s0]=v0; buf[s1]=v1;
    __syncthreads();
  }
  for (int s=tid; s<512; s+=256){
    float c = buf[s];
    if (s<S_){
      cs1[bh*512+s]=c;
      float gv = igb[bh*512+s]-c;
      g[bh*512+s]=gv;
      buf2[s]=gv;
    } else buf2[s] = -3.4e38f;
  }
  __syncthreads();
  for (int off=1; off<512; off<<=1){
    int s0=tid, s1=tid+256;
    float v0 = fmaxf(buf2[s0], (s0>=off)? buf2[s0-off] : -3.4e38f);
    float v1 = fmaxf(buf2[s1], (s1>=off)? buf2[s1-off] : -3.4e38f);
    __syncthreads();
    buf2[s0]=v0; buf2[s1]=v1;
    __syncthreads();
  }
  for (int s=tid; s<S_; s+=256) M[bh*512+s] = buf2[s];
}

// ---------------- tiled attention: MFMA (pre-split bf16) flash-style + fused hout ----------------
#define TQ 32
#define TS 32
__global__ __launch_bounds__(256) void k_attn(
  const bf16* __restrict__ qhi, const bf16* __restrict__ qlo,
  const bf16* __restrict__ khi, const bf16* __restrict__ klo,
  const bf16* __restrict__ vhi, const bf16* __restrict__ vlo,
  const float* __restrict__ cs1, const float* __restrict__ g, const float* __restrict__ M,
  const float* __restrict__ onw, const float* __restrict__ skip,
  const float* __restrict__ xc, const float* __restrict__ zA,
  bf16* __restrict__ out16)
{
  __shared__ __align__(16) u16 vThi[128][40];
  __shared__ __align__(16) u16 vTlo[128][40];
  __shared__ __align__(16) u16 phi[32][40];
  __shared__ __align__(16) u16 plo[32][40];
  __shared__ float MtS[32], cssS[32], normS[32], muS[32], rsS[32];
  __shared__ float lsumW[2][32], sumA[2][32], sumB[2][32];

  int tq = blockIdx.x, bh = blockIdx.y;
  int b = bh>>2, h = bh&3;
  int tid = threadIdx.x;
  int wv = tid>>6;
  int tw = wv&1, sw = wv>>1;     // sw = QK s-half; doubles as PV d-half
  int l = tid&63;
  int lr = l&15, lg = l>>4;
  int t0 = tq*TQ;
  const float sc = 0.08838834764831843f;

  if (tid < 32){
    int t = t0 + tid; int tc = (t<S_)? t : (S_-1);
    MtS[tid]  = M[bh*512 + tc];
    cssS[tid] = cs1[bh*512 + tc];
  }

  bf16x8v qh[4], ql[4];
  {
    size_t qoff = ((size_t)(b*S_ + t0 + tw*16 + lr))*512 + h*128 + lg*8;
    #pragma unroll
    for(int k0=0;k0<4;k0++){
      qh[k0] = *(const bf16x8v*)(qhi + qoff + k0*32);
      ql[k0] = *(const bf16x8v*)(qlo + qoff + k0*32);
    }
  }

  f32x4v accpv[4] = {};
  float lsum[4] = {0.f,0.f,0.f,0.f};

  int t1 = min(t0+TQ, S_);
  int sp = tid>>4, dl = tid&15;   // V-transpose staging coords

  __syncthreads();

  for (int s0=0; s0<t1; s0+=TS){
    bf16x8v kh[4], kl2[4];
    {
      size_t koff = ((size_t)(b*S_ + s0 + sw*16 + lr))*512 + h*128 + lg*8;
      #pragma unroll
      for(int k0=0;k0<4;k0++){
        kh[k0]  = *(const bf16x8v*)(khi + koff + k0*32);
        kl2[k0] = *(const bf16x8v*)(klo + koff + k0*32);
      }
    }
    u16 vha[8], vhb[8], vla[8], vlb[8];
    {
      const u16* ha = (const u16*)vhi + ((size_t)(b*S_ + s0 + 2*sp))*512 + h*128 + dl;
      const u16* la = (const u16*)vlo + ((size_t)(b*S_ + s0 + 2*sp))*512 + h*128 + dl;
      #pragma unroll
      for(int j=0;j<8;j++){
        vha[j]=ha[16*j]; vhb[j]=ha[512+16*j];
        vla[j]=la[16*j]; vlb[j]=la[512+16*j];
      }
    }
    float g_s = g[bh*512 + s0 + sw*16 + lr];

    f32x4v cqk = {0.f,0.f,0.f,0.f};
    #pragma unroll
    for(int k0=0;k0<4;k0++){
      cqk = __builtin_amdgcn_mfma_f32_16x16x32_bf16(qh[k0], kh[k0],  cqk, 0,0,0);
      cqk = __builtin_amdgcn_mfma_f32_16x16x32_bf16(qh[k0], kl2[k0], cqk, 0,0,0);
      cqk = __builtin_amdgcn_mfma_f32_16x16x32_bf16(ql[k0], kh[k0],  cqk, 0,0,0);
    }

    int s_g = s0 + sw*16 + lr;
    u16 pw_h[4], pw_l[4];
    #pragma unroll
    for(int r=0;r<4;r++){
      int tl = tw*16 + lg*4 + r;
      int t_row = t0 + tl;
      float wvv = ((s_g <= t_row) && (t_row < S_)) ? cqk[r]*sc*expneg_(g_s - MtS[tl]) : 0.f;
      lsum[r] += wvv;
      bf16 hh = __float2bfloat16(wvv);
      float hf = __bfloat162float(hh);
      bf16 ll = __float2bfloat16(wvv - hf);
      __builtin_memcpy(&pw_h[r], &hh, 2);
      __builtin_memcpy(&pw_l[r], &ll, 2);
    }

    __syncthreads();

    #pragma unroll
    for(int r=0;r<4;r++){
      int tl = tw*16 + lg*4 + r;
      phi[tl][sw*16 + lr] = pw_h[r];
      plo[tl][sw*16 + lr] = pw_l[r];
    }
    {
      unsigned* vh32 = (unsigned*)&vThi[0][0];
      unsigned* vl32 = (unsigned*)&vTlo[0][0];
      #pragma unroll
      for(int j=0;j<8;j++){
        int d = dl + 16*j;
        vh32[d*20 + sp] = (unsigned)vha[j] | ((unsigned)vhb[j]<<16);
        vl32[d*20 + sp] = (unsigned)vla[j] | ((unsigned)vlb[j]<<16);
      }
    }

    __syncthreads();

    bf16x8v pah = *(const bf16x8v*)((const void*)(&phi[tw*16 + lr][0] + lg*8));
    bf16x8v pal = *(const bf16x8v*)((const void*)(&plo[tw*16 + lr][0] + lg*8));
    #pragma unroll
    for(int fd=0; fd<4; fd++){
      bf16x8v vbh = *(const bf16x8v*)((const void*)(&vThi[sw*64 + fd*16 + lr][0] + lg*8));
      bf16x8v vbl = *(const bf16x8v*)((const void*)(&vTlo[sw*64 + fd*16 + lr][0] + lg*8));
      accpv[fd] = __builtin_amdgcn_mfma_f32_16x16x32_bf16(pah, vbh, accpv[fd], 0,0,0);
      accpv[fd] = __builtin_amdgcn_mfma_f32_16x16x32_bf16(pah, vbl, accpv[fd], 0,0,0);
      accpv[fd] = __builtin_amdgcn_mfma_f32_16x16x32_bf16(pal, vbh, accpv[fd], 0,0,0);
    }
  }

  #pragma unroll
  for(int r=0;r<4;r++){
    #pragma unroll
    for(int m=1;m<16;m<<=1) lsum[r] += __shfl_xor(lsum[r], m, 16);
  }
  if (lr==0){
    #pragma unroll
    for(int r=0;r<4;r++) lsumW[sw][tw*16 + lg*4 + r] = lsum[r];
  }
  __syncthreads();
  if (tid < 32){
    float ls = lsumW[0][tid] + lsumW[1][tid];
    float maxD = cssS[tid] + MtS[tid];
    float nrm = fmaxf(fabsf(ls), expclamp_(-maxD));
    normS[tid] = rcp_(nrm + 1e-6f);
  }
  __syncthreads();

  float o_[4][4];
  float srow[4]={0.f,0.f,0.f,0.f}, sq[4]={0.f,0.f,0.f,0.f};
  #pragma unroll
  for(int r=0;r<4;r++){
    float scl = normS[tw*16 + lg*4 + r];
    #pragma unroll
    for(int fd=0;fd<4;fd++){
      float o = accpv[fd][r]*scl;
      o_[fd][r] = o;
      srow[r] += o; sq[r] += o*o;
    }
  }
  #pragma unroll
  for(int r=0;r<4;r++){
    #pragma unroll
    for(int m=1;m<16;m<<=1){ srow[r]+=__shfl_xor(srow[r],m,16); sq[r]+=__shfl_xor(sq[r],m,16); }
  }
  if (lr==0){
    #pragma unroll
    for(int r=0;r<4;r++){ sumA[sw][tw*16+lg*4+r]=srow[r]; sumB[sw][tw*16+lg*4+r]=sq[r]; }
  }
  __syncthreads();
  if (tid < 32){
    float mu = (sumA[0][tid]+sumA[1][tid])*(1.f/128.f);
    float ex2= (sumB[0][tid]+sumB[1][tid])*(1.f/128.f);
    muS[tid]=mu;
    rsS[tid]=rsqrtf(fmaxf(ex2 - mu*mu, 0.f)+EPS_);
  }
  __syncthreads();

  #pragma unroll
  for(int fd=0; fd<4; fd++){
    int d = sw*64 + fd*16 + lr;
    float ow = onw[h*128 + d];
    float sk = skip[h*128 + d];
    #pragma unroll
    for(int r=0;r<4;r++){
      int tl = tw*16 + lg*4 + r;
      int t = t0 + tl;
      if (t < S_){
        size_t row = (size_t)(b*S_+t);
        float hf = (o_[fd][r]-muS[tl])*rsS[tl]*ow;
        float xcv = xc[row*512 + h*128 + d];
        float zv  = zA[row*1024 + 512 + h*128 + d];
        out16[row*512 + h*128 + d] = __float2bfloat16((hf + sk*xcv)*silu_(zv));
      }
    }
  }
}

// ---------------- FUSED S-block: LN1 + causal conv(256) + wx (16-row tiles x 4 g-blocks) --------
// h (LN1 out) and hc (conv out) became kernel-local after the attn fusions -> keep them in LDS.
// Block (rt,g): rows [rt*16, rt*16+16). LN computed for rows rt*16-3..rt*16+15 (wave-per-row,
// shfl reductions); conv from LDS h with the same ss>=0 batch guard; wx identical inner loop /
// summation order as the old k_wx (bit-identical wx output).
#define SWR 16
__global__ __launch_bounds__(256) void k_swx(
  const float* __restrict__ x, const float* __restrict__ ln1w,
  const float* __restrict__ cw, const float* __restrict__ cb,
  const float* __restrict__ gwT, const float* __restrict__ gb,
  float* __restrict__ wx)
{
  __shared__ __align__(16) float hs[SWR+3][260];
  __shared__ __align__(16) float hcs[SWR][260];
  int rt = blockIdx.x, g = blockIdx.y;
  int tid = threadIdx.x;
  int wv = tid>>6, lane = tid&63;
  int r0 = rt*SWR;
  if (r0 >= NROW) return;
  // --- LN rows r0-3 .. r0+SWR-1 (wave-per-row, 4 cols/lane) ---
  for (int i=wv; i<SWR+3; i+=4){
    int r = r0 - 3 + i;
    if (r < 0 || r >= NROW){
      for(int c=lane;c<256;c+=64) hs[i][c]=0.f;
      continue;
    }
    const float* xr = x + (size_t)r*256;
    float v0=xr[lane], v1=xr[lane+64], v2=xr[lane+128], v3=xr[lane+192];
    float s_ = v0+v1+v2+v3;
    for(int m=32;m;m>>=1) s_ += __shfl_xor(s_,m,64);
    float mu = s_*(1.f/256.f);
    float d0=v0-mu,d1=v1-mu,d2=v2-mu,d3=v3-mu;
    float q_ = d0*d0+d1*d1+d2*d2+d3*d3;
    for(int m=32;m;m>>=1) q_ += __shfl_xor(q_,m,64);
    float rs = rsqrtf(q_*(1.f/256.f)+EPS_);
    hs[i][lane]     = d0*rs*ln1w[lane];
    hs[i][lane+64]  = d1*rs*ln1w[lane+64];
    hs[i][lane+128] = d2*rs*ln1w[lane+128];
    hs[i][lane+192] = d3*rs*ln1w[lane+192];
  }
  __syncthreads();
  // --- conv+silu rows r0..r0+SWR-1 (thread=col) ---
  {
    int c = tid;
    if (c < 256){
      for (int rr=0; rr<SWR; ++rr){
        int r = r0+rr;
        if (r>=NROW) break;
        int s = r % S_;
        float acc = cb[c];
        #pragma unroll
        for(int j=0;j<4;j++){
          int ss = s-3+j;
          if (ss>=0) acc += cw[c*4+j]*hs[rr+j][c];
        }
        hcs[rr][c] = silu_(acc);
      }
    }
  }
  __syncthreads();
  // --- wx (g fixed per block), identical inner loop to old k_wx ---
  int n = tid>>6, e = tid&63;
  float W[64];
  #pragma unroll
  for(int d=0;d<64;d++) W[d] = gwT[(size_t)(((g*4+n)*64+d))*64 + e];
  float bias = gb[(g*4+n)*64+e];
  for (int rr=0; rr<SWR; ++rr){
    int r = r0+rr;
    if (r>=NROW) break;
    const float* hrow = (g<2)? &hcs[rr][n*64] : &hs[rr+3][n*64];
    float a0=0,a1=0,a2=0,a3=0;
    #pragma unroll
    for(int d=0;d<64;d+=4){
      float4 hv = *(const float4*)&hrow[d];   // wave-uniform address -> LDS broadcast
      a0+=hv.x*W[d]; a1+=hv.y*W[d+1]; a2+=hv.z*W[d+2]; a3+=hv.w*W[d+3];
    }
    int b=r/S_, s=r%S_;
    wx[(((size_t)(b*4+n)*512 + s)*256) + e*4 + g] = bias + ((a0+a1)+(a2+a3));
  }
}

// ---------------- sLSTM scan: 4 waves per chain, LDS y-exchange, exp-domain cell ----------------
__global__ __launch_bounds__(256,1) void k_scan(
  const float* __restrict__ wx, const bf16* __restrict__ wf, float* __restrict__ y_out)
{
  int bn = blockIdx.x; int b = bn>>2, n = bn&3;
  int tid = threadIdx.x;
  int w = tid>>6;                  // wave id = e-block
  int l = tid&63;
  int q = l>>4;
  int el = l&15;
  int e  = w*16 + el;

  __shared__ __align__(16) unsigned short ybuf[2][64];   // bf16 bits, double-buffered

  if (tid < 128) ((unsigned short*)ybuf)[tid] = 0;       // y_{-1} = 0 (both slots)
  __syncthreads();

  bf16x8v Wf2[4][2];
  #pragma unroll
  for(int g=0; g<4; ++g){
    #pragma unroll
    for(int kf=0; kf<2; ++kf){
      Wf2[g][kf] = *(const bf16x8v*)(wf + ((size_t)((n*16 + (4*g+w))*2 + kf)*64 + l)*8);
    }
  }

  const float* wxBase = wx + ((size_t)bn*512)*256 + e*4;
  float* yst = y_out + (size_t)(b*S_)*256 + n*64 + e;

  float4 p0,p1,p2,p3;
  p0 = *(const float4*)(wxBase + (size_t)0*256);
  p1 = *(const float4*)(wxBase + (size_t)1*256);
  p2 = *(const float4*)(wxBase + (size_t)2*256);
  p3 = *(const float4*)(wxBase + (size_t)3*256);

  f32x4v z4 = {0.f,0.f,0.f,0.f};
  float c=0.f, nn=0.f, pm=1.f;     // pm = exp(m), m0 = 0

  for (int s=0; s<S_; ++s){
    int p = s&1;
    bf16x8v a0 = *(const bf16x8v*)&ybuf[p][16*q];
    bf16x8v a1 = *(const bf16x8v*)&ybuf[p][16*q+8];

    f32x4v acc0,acc1,acc2,acc3, accb0,accb1,accb2,accb3;
    acc0  = __builtin_amdgcn_mfma_f32_16x16x32_bf16(a0, Wf2[0][0], z4, 0,0,0);
    acc1  = __builtin_amdgcn_mfma_f32_16x16x32_bf16(a0, Wf2[1][0], z4, 0,0,0);
    acc2  = __builtin_amdgcn_mfma_f32_16x16x32_bf16(a0, Wf2[2][0], z4, 0,0,0);
    acc3  = __builtin_amdgcn_mfma_f32_16x16x32_bf16(a0, Wf2[3][0], z4, 0,0,0);
    accb0 = __builtin_amdgcn_mfma_f32_16x16x32_bf16(a1, Wf2[0][1], z4, 0,0,0);
    accb1 = __builtin_amdgcn_mfma_f32_16x16x32_bf16(a1, Wf2[1][1], z4, 0,0,0);
    accb2 = __builtin_amdgcn_mfma_f32_16x16x32_bf16(a1, Wf2[2][1], z4, 0,0,0);
    accb3 = __builtin_amdgcn_mfma_f32_16x16x32_bf16(a1, Wf2[3][1], z4, 0,0,0);

    float4 wg = p0; p0=p1; p1=p2; p2=p3;
    { int sp = s+4; if (sp>510) sp=510;
      p3 = *(const float4*)(wxBase + (size_t)sp*256); }

    float iraw=acc0[0]+accb0[0]+wg.x, fraw=acc1[0]+accb1[0]+wg.y;
    float zraw=acc2[0]+accb2[0]+wg.z, oraw=acc3[0]+accb3[0]+wg.w;

    float pe  = __expf(fminf(iraw, 80.f));
    float ef  = __expf(-fraw);
    float e2z = __expf(2.f*zraw);
    float eo  = __expf(-oraw);
    float sf  = rcp_(1.f+ef);
    float ps  = pm*sf;
    float pn  = fmaxf(fmaxf(pe, ps), 1e-30f);
    float rpn = rcp_(pn);
    float fg  = ps*rpn;
    float ig  = pe*rpn;
    float th  = 1.f - 2.f*rcp_(e2z+1.f);
    c  = fg*c + ig*th;
    nn = fmaxf(fg*nn + ig, 1e-30f);
    float y = rcp_(1.f+eo) * c * rcp_(nn);
    pm = pn;

    bf16 hb = __float2bfloat16(y);
    unsigned short hbits; __builtin_memcpy(&hbits,&hb,2);
    if (l < 16){
      ybuf[p^1][e] = hbits;
      yst[(size_t)s*256] = y;
    }
    asm volatile("s_waitcnt lgkmcnt(0)" ::: "memory");
    __builtin_amdgcn_s_barrier();
    asm volatile("" ::: "memory");
    __builtin_amdgcn_sched_barrier(0);
  }
}

// ---------------- yn-add + fused LN2 -> bf16 (shfl reductions) ----------------
__global__ __launch_bounds__(256) void k_ynadd_ln2(
  const float* __restrict__ y, const float* __restrict__ gn,
  float* __restrict__ x, const float* __restrict__ ln2w, bf16* __restrict__ h16)
{
  __shared__ float pA[4], pB[4];
  int r=blockIdx.x, t=threadIdx.x;
  float xv = x[(size_t)r*256+t];
  if (r < NROW){
    float v=y[(size_t)r*256+t];
    float s=v;
    for(int m=32;m;m>>=1) s+=__shfl_xor(s,m,64);
    float mu=s*(1.f/64.f);
    float d=v-mu;
    float q=d*d;
    for(int m=32;m;m>>=1) q+=__shfl_xor(q,m,64);
    float var=q*(1.f/64.f);
    xv += d*rsqrtf(var+EPS_)*gn[t];
    x[(size_t)r*256+t]=xv;
  }
  float s2 = xv;
  for(int m=32;m;m>>=1) s2 += __shfl_xor(s2,m,64);
  if((t&63)==0) pA[t>>6]=s2;
  __syncthreads();
  float mu2=(pA[0]+pA[1]+pA[2]+pA[3])*(1.f/E_);
  float dd=xv-mu2;
  float q2=dd*dd;
  for(int m=32;m;m>>=1) q2 += __shfl_xor(q2,m,64);
  if((t&63)==0) pB[t>>6]=q2;
  __syncthreads();
  float var2=(pB[0]+pB[1]+pB[2]+pB[3])*(1.f/E_);
  h16[(size_t)r*256+t]=__float2bfloat16(dd*rsqrtf(var2+EPS_)*ln2w[t]);
}

// ---------------- fused postnorm-LN + cq build -> bf16 (shfl reductions) ----------------
__global__ __launch_bounds__(256) void k_cq_ln(
  const float* __restrict__ x, const float* __restrict__ pw,
  const float* __restrict__ qe, const float* __restrict__ pide, const int* __restrict__ tgt,
  bf16* __restrict__ cq)
{
  __shared__ float pA[4], pB[4];
  int r=blockIdx.x, t=threadIdx.x;
  float v = x[(size_t)r*256+t];
  float s_=v;
  for(int m=32;m;m>>=1) s_ += __shfl_xor(s_,m,64);
  if((t&63)==0) pA[t>>6]=s_;
  __syncthreads();
  float mu=(pA[0]+pA[1]+pA[2]+pA[3])*(1.f/E_);
  float d=v-mu;
  float q_=d*d;
  for(int m=32;m;m>>=1) q_ += __shfl_xor(q_,m,64);
  if((t&63)==0) pB[t>>6]=q_;
  __syncthreads();
  float var=(pB[0]+pB[1]+pB[2]+pB[3])*(1.f/E_);
  float dv = d*rsqrtf(var+EPS_)*pw[t];
  float pe=pide[r]; int tg=tgt[r];
  size_t base=(size_t)r*1024;
  cq[base+t]=__float2bfloat16(dv-pe);
  cq[base+256+t]=__float2bfloat16(qe[(size_t)r*256+t]);
  cq[base+512+t]=__float2bfloat16((tg==1)? dv:0.f);
  cq[base+768+t]=__float2bfloat16((tg==0)? dv:0.f);
}

// ---------------- final: selected logit + sigmoid (shfl reduction) ----------------
__global__ __launch_bounds__(256) void k_final(
  const float* __restrict__ o2, const float* __restrict__ w3, const float* __restrict__ b3,
  const int* __restrict__ qsh, float* __restrict__ out)
{
  __shared__ float pA[4];
  int r=blockIdx.x, t=threadIdx.x;
  int qi=qsh[r];
  float p=o2[(size_t)r*256+t]*w3[(size_t)qi*256+t];
  for(int m=32;m;m>>=1) p += __shfl_xor(p,m,64);
  if((t&63)==0) pA[t>>6]=p;
  __syncthreads();
  if(t==0) out[r]=sig_(pA[0]+pA[1]+pA[2]+pA[3]+b3[qi]);
}

// ---------------- launch ----------------
extern "C" void kernel_launch(void* const* d_in, const int* in_sizes, int n_in,
                              void* d_out, int out_size, void* d_ws, size_t ws_size,
                              hipStream_t stream) {
  const int* questions = (const int*)d_in[0];
  const int* responses = (const int*)d_in[1];
  const int* skills    = (const int*)d_in[2];
  const float* q_embed       = (const float*)d_in[4];
  const float* qa_embed      = (const float*)d_in[5];
  const float* q_embed_diff  = (const float*)d_in[6];
  const float* qa_embed_diff = (const float*)d_in[7];
  const float* difficult_param=(const float*)d_in[8];
  const float* ln0_w   = (const float*)d_in[9];
  const float* m_up_w  = (const float*)d_in[10];
  const float* m_up_b  = (const float*)d_in[11];
  const float* m_conv_w= (const float*)d_in[12];
  const float* m_conv_b= (const float*)d_in[13];
  const float* m_q_w   = (const float*)d_in[14];
  const float* m_k_w   = (const float*)d_in[15];
  const float* m_v_w   = (const float*)d_in[16];
  const float* m_ig_w  = (const float*)d_in[17];
  const float* m_ig_b  = (const float*)d_in[18];
  const float* m_fg_w  = (const float*)d_in[19];
  const float* m_fg_b  = (const float*)d_in[20];
  const float* m_outnorm_w=(const float*)d_in[21];
  const float* m_skip  = (const float*)d_in[22];
  const float* m_down_w= (const float*)d_in[23];
  const float* m_down_b= (const float*)d_in[24];
  const float* ln1_w   = (const float*)d_in[25];
  const float* s_conv_w= (const float*)d_in[26];
  const float* s_conv_b= (const float*)d_in[27];
  const float* s_gate_w= (const float*)d_in[28];
  const float* s_rec_w = (const float*)d_in[29];
  const float* s_bias  = (const float*)d_in[30];
  const float* s_gn_w  = (const float*)d_in[31];
  const float* ln2_w   = (const float*)d_in[32];
  const float* ffn_up_w= (const float*)d_in[33];
  const float* ffn_up_b= (const float*)d_in[34];
  const float* ffn_down_w=(const float*)d_in[35];
  const float* ffn_down_b=(const float*)d_in[36];
  const float* postnorm_w=(const float*)d_in[37];
  const float* out_w1  = (const float*)d_in[38];
  const float* out_b1  = (const float*)d_in[39];
  const float* out_w2  = (const float*)d_in[40];
  const float* out_b2  = (const float*)d_in[41];
  const float* out_w3  = (const float*)d_in[42];
  const float* out_b3  = (const float*)d_in[43];

  float* ws = (float*)d_ws;
  const size_t R = (size_t)NP_*256;
  float* x    = ws;
  float* qe   = ws + R;
  float* h    = ws + 2*R;        // holds hout16 during attn
  float* t256 = ws + 3*R;        // early: split-bf16 LN0 output (h_hi/h_lo); late: out_w2 result
  float* A    = ws + 4*R;        // NP x 1024 ; also scan-layout wx
  float* Bb   = ws + 8*R;        // NP x 512 (xc)
  float* Cb   = ws + 10*R;       // NP x 512  (q hi/lo; later b16)
  float* Db   = ws + 12*R;       // NP x 512  (k hi/lo; later ffg16)
  float* Eb   = ws + 14*R;       // NP x 512  (v hi/lo; later cq16)
  float* pide = ws + 16*R;
  int*   tgt  = (int*)(ws + 16*R + NP_);
  int*   qsh  = (int*)(ws + 16*R + 2*NP_);
  float* igb  = ws + 16*R + 3*NP_;
  float* fgb  = igb + 64*512;
  float* cs1  = fgb + 64*512;
  float* gdec = cs1 + 64*512;
  float* Mrun = gdec + 64*512;
  bf16* wpool = (bf16*)(Mrun + 64*512);
  bf16* m_down_w16  = wpool;
  bf16* ffn_up_w16  = m_down_w16 + 256*512;
  bf16* ffn_down_w16= ffn_up_w16 + 768*256;
  bf16* out_w1_16   = ffn_down_w16 + 256*384;
  bf16* out_w2_16   = out_w1_16 + 512*1024;
  bf16* h16         = out_w2_16 + 256*512;
  bf16* m_up_whi    = h16 + (size_t)NP_*256;     // 1024*256
  bf16* m_up_wlo    = m_up_whi + 1024*256;       // 1024*256
  float* gwT        = (float*)(m_up_wlo + 1024*256);  // 16*64*64 floats
  bf16* wfrag       = (bf16*)(gwT + 16*64*64);   // 65536 bf16: MFMA B-frags of s_rec_w
  bf16* q_hi = (bf16*)Cb;  bf16* q_lo = q_hi + (size_t)NP_*512;
  bf16* k_hi = (bf16*)Db;  bf16* k_lo = k_hi + (size_t)NP_*512;
  bf16* v_hi = (bf16*)Eb;  bf16* v_lo = v_hi + (size_t)NP_*512;
  bf16* hout16 = (bf16*)h;                       // NP*512 bf16
  bf16* ffg16  = (bf16*)Db;
  bf16* cq16   = (bf16*)Eb;
  bf16* b16    = (bf16*)Cb;
  bf16* h_hi   = (bf16*)t256;                    // NP*256
  bf16* h_lo   = h_hi + (size_t)NP_*256;         // NP*256

  // ---- one-shot weight prep ----
  k_prep<<<5760,256,0,stream>>>(
      m_down_w, m_down_w16, ffn_up_w, ffn_up_w16, ffn_down_w, ffn_down_w16,
      out_w1, out_w1_16, out_w2, out_w2_16, m_up_w, m_up_whi, m_up_wlo,
      s_gate_w, gwT, s_rec_w, wfrag);

  // ---- embeddings (+LN0 -> split bf16) ----
  k_embed<<<NP_,256,0,stream>>>(questions,responses,skills,q_embed,qa_embed,
      q_embed_diff,qa_embed_diff,difficult_param, ln0_w, x,qe, h_hi,h_lo, pide,tgt,qsh);
  // ---- block M ----
  k_gemm16s<<<dim3(1024/64,NP_/64),256,0,stream>>>(h_hi,h_lo, m_up_whi,m_up_wlo, m_up_b, A, 1024,256);
  k_mega<<<NP_,256,0,stream>>>(A, m_conv_w,m_conv_b, m_q_w,m_k_w,m_v_w,
      m_ig_w,m_ig_b,m_fg_w,m_fg_b, Bb, q_hi,q_lo, k_hi,k_lo, v_hi,v_lo, igb,fgb);
  k_decay<<<64,256,0,stream>>>(igb,fgb, cs1,gdec,Mrun);
  hipMemsetAsync(hout16 + (size_t)NROW*512, 0, (size_t)(NP_-NROW)*512*sizeof(bf16), stream);
  k_attn<<<dim3((S_+TQ-1)/TQ, B_*NH_),256,0,stream>>>(q_hi,q_lo, k_hi,k_lo, v_hi,v_lo,
      cs1,gdec,Mrun, m_outnorm_w, m_skip, Bb, A, hout16);
  k_gemm16<<<dim3(256/64,NP_/64),256,0,stream>>>(hout16, m_down_w16, m_down_b, x, x, (bf16*)nullptr, 256,512,0);
  // ---- block S (fused LN1+conv+wx) ----
  k_swx<<<dim3((NROW+SWR-1)/SWR,4),256,0,stream>>>(x, ln1_w, s_conv_w, s_conv_b, gwT, s_bias, A);
  k_scan<<<64,256,0,stream>>>(A, wfrag, Cb);
  k_ynadd_ln2<<<NP_,256,0,stream>>>(Cb, s_gn_w, x, ln2_w, h16);
  // ---- FFN (fused up-proj + relu-mul) ----
  k_gemm16f<<<dim3(768/64,NP_/64),256,0,stream>>>(h16, ffn_up_w16, ffn_up_b, ffg16, 256);
  k_gemm16<<<dim3(256/64,NP_/64),256,0,stream>>>(ffg16, ffn_down_w16, ffn_down_b, x, x, (bf16*)nullptr, 256,384,0);
  // ---- output head ----
  k_cq_ln<<<NP_,256,0,stream>>>(x, postnorm_w, qe, pide, tgt, cq16);
  k_gemm16<<<dim3(512/64,NP_/64),256,0,stream>>>(cq16, out_w1_16, out_b1, (const float*)nullptr, (float*)nullptr, b16, 512,1024,1);
  k_gemm16<<<dim3(256/64,NP_/64),256,0,stream>>>(b16, out_w2_16, out_b2, (const float*)nullptr, t256, (bf16*)nullptr, 256,512,1);
  k_final<<<NROW,256,0,stream>>>(t256, out_w3, out_b3, qsh, (float*)d_out);
}

// Round 14
// 797.341 us; speedup vs baseline: 1.0201x; 1.0201x over previous
//
#include <hip/hip_runtime.h>
#include <hip/hip_bf16.h>

// ---------------- constants ----------------
#define B_    16
#define SL_   512
#define S_    511
#define E_    256
#define NH_   4
#define I_    512
#define DHM_  128
#define DHS_  64
#define F_    384
#define NP_   8192               // padded row count (multiple of 64)
#define NROW  (B_*S_)            // 8176 real rows
#define EPS_  1e-5f

typedef __hip_bfloat16 bf16;
typedef unsigned short u16;
typedef __bf16 bf16x8v __attribute__((ext_vector_type(8)));
typedef float  f32x4v  __attribute__((ext_vector_type(4)));

__device__ __forceinline__ float rcp_(float x){ return __builtin_amdgcn_rcpf(x); }
__device__ __forceinline__ float sig_(float x){ return rcp_(1.f+__expf(-x)); }
__device__ __forceinline__ float silu_(float x){ return x*sig_(x); }
__device__ __forceinline__ float logsig_(float x){ return fminf(x,0.f) - __logf(1.f + __expf(-fabsf(x))); }
__device__ __forceinline__ float expneg_(float x){ return __expf(fminf(x,0.f)); }
__device__ __forceinline__ float expclamp_(float x){ return __expf(fminf(fmaxf(x,-80.f),80.f)); }
__device__ __forceinline__ float tanh_(float x){ return 1.f - 2.f*rcp_(__expf(2.f*x)+1.f); }

// ---------------- ONE-SHOT prep: all weight conversions in a single kernel ----------------
__global__ __launch_bounds__(256) void k_prep(
  const float* __restrict__ m_down_w, bf16* __restrict__ m_down_w16,
  const float* __restrict__ ffn_up_w, bf16* __restrict__ ffn_up_w16,
  const float* __restrict__ ffn_down_w, bf16* __restrict__ ffn_down_w16,
  const float* __restrict__ out_w1, bf16* __restrict__ out_w1_16,
  const float* __restrict__ out_w2, bf16* __restrict__ out_w2_16,
  const float* __restrict__ m_up_w, bf16* __restrict__ m_up_whi, bf16* __restrict__ m_up_wlo,
  const float* __restrict__ s_gate_w, float* __restrict__ gwT,
  const float* __restrict__ s_rec_w, bf16* __restrict__ wfrag)
{
  int i = blockIdx.x*256 + threadIdx.x;
  if (i < 131072){ m_down_w16[i] = __float2bfloat16(m_down_w[i]); return; }
  i -= 131072;
  if (i < 196608){              // ffn_up: dst row 2j+p = src row j + p*F
    int rp=i>>8, c=i&255; int j=rp>>1, p=rp&1;
    ffn_up_w16[i] = __float2bfloat16(ffn_up_w[(size_t)(j + p*F_)*E_ + c]); return;
  }
  i -= 196608;
  if (i < 98304){ ffn_down_w16[i] = __float2bfloat16(ffn_down_w[i]); return; }
  i -= 98304;
  if (i < 524288){ out_w1_16[i] = __float2bfloat16(out_w1[i]); return; }
  i -= 524288;
  if (i < 131072){ out_w2_16[i] = __float2bfloat16(out_w2[i]); return; }
  i -= 131072;
  if (i < 262144){
    float v = m_up_w[i];
    bf16 h = __float2bfloat16(v);
    m_up_whi[i]=h;
    m_up_wlo[i]=__float2bfloat16(v-__bfloat162float(h));
    return;
  }
  i -= 262144;
  if (i < 65536){               // gwT[blk][d][e] = s_gate_w[blk][e][d]
    int blk=i>>12, d=(i>>6)&63, e=i&63;
    gwT[(size_t)(blk*64+d)*64+e] = s_gate_w[(size_t)(blk*64+e)*64+d]; return;
  }
  i -= 65536;
  {                             // wfrag (K-permuted MFMA B-frags of s_rec_w)
    int j=i&7, l=(i>>3)&63, kf=(i>>9)&1, t=(i>>10)&15, n=i>>14;
    int g=t>>2;
    int e=(t&3)*16 + (l&15);
    int d=(l>>4)*16 + kf*8 + j;
    wfrag[i] = __float2bfloat16(s_rec_w[((size_t)((g*4+n)*64 + d))*64 + e]);
  }
}

// ---------------- embedding gather + fused LN0 -> split bf16 (shfl reductions) ----------------
__global__ __launch_bounds__(256) void k_embed(
  const int* __restrict__ questions, const int* __restrict__ responses, const int* __restrict__ skills,
  const float* __restrict__ q_embed, const float* __restrict__ qa_embed,
  const float* __restrict__ q_embed_diff, const float* __restrict__ qa_embed_diff,
  const float* __restrict__ difficult_param, const float* __restrict__ ln0w,
  float* __restrict__ x, float* __restrict__ qe,
  bf16* __restrict__ h_hi, bf16* __restrict__ h_lo,
  float* __restrict__ pide, int* __restrict__ tgt, int* __restrict__ qsh)
{
  __shared__ float pA[4], pB[4];
  int r = blockIdx.x; int e = threadIdx.x;
  float xa = 0.f;
  if (r < NROW){
    int b = r / S_, s = r % S_;
    int pid  = questions[b*SL_+s];
    int qd   = skills[b*SL_+s];
    int resp = responses[b*SL_+s];
    int t    = (resp > -1) ? resp : 0;
    float pe = difficult_param[pid];
    float q0 = q_embed[qd*E_+e];
    xa = q0 + qa_embed[t*E_+e] + pe*qa_embed_diff[t*E_+e];
    float qn = q0 + pe*q_embed_diff[qd*E_+e];
    x[(size_t)r*E_+e]=xa; qe[(size_t)r*E_+e]=qn;
    if (e==0){ pide[r]=pe; tgt[r]=t; qsh[r]=skills[b*SL_+s+1]; }
  } else {
    x[(size_t)r*E_+e]=0.f; qe[(size_t)r*E_+e]=0.f;
    if (e==0){ pide[r]=0.f; tgt[r]=-7; qsh[r]=0; }
  }
  float s_ = xa;
  for(int m=32;m;m>>=1) s_ += __shfl_xor(s_,m,64);
  if((e&63)==0) pA[e>>6]=s_;
  __syncthreads();
  float mu = (pA[0]+pA[1]+pA[2]+pA[3])*(1.f/E_);
  float d = xa-mu;
  float q_ = d*d;
  for(int m=32;m;m>>=1) q_ += __shfl_xor(q_,m,64);
  if((e&63)==0) pB[e>>6]=q_;
  __syncthreads();
  float var = (pB[0]+pB[1]+pB[2]+pB[3])*(1.f/E_);
  float o = d*rsqrtf(var+EPS_)*ln0w[e];
  bf16 hv = __float2bfloat16(o);
  h_hi[(size_t)r*E_+e] = hv;
  h_lo[(size_t)r*E_+e] = __float2bfloat16(o-__bfloat162float(hv));
}

// ---------------- layernorm over E=256 (used for ln1) ----------------
__global__ __launch_bounds__(256) void k_ln(
  const float* __restrict__ in, const float* __restrict__ w, float* __restrict__ out)
{
  __shared__ float pA[4], pB[4];
  int r = blockIdx.x, t = threadIdx.x;
  float v = in[(size_t)r*E_+t];
  float s_ = v;
  for(int m=32;m;m>>=1) s_ += __shfl_xor(s_,m,64);
  if((t&63)==0) pA[t>>6]=s_;
  __syncthreads();
  float mu = (pA[0]+pA[1]+pA[2]+pA[3])*(1.f/E_);
  float d = v-mu;
  float q_ = d*d;
  for(int m=32;m;m>>=1) q_ += __shfl_xor(q_,m,64);
  if((t&63)==0) pB[t>>6]=q_;
  __syncthreads();
  float var = (pB[0]+pB[1]+pB[2]+pB[3])*(1.f/E_);
  out[(size_t)r*E_+t] = d*rsqrtf(var+EPS_)*w[t];
}

// ---------------- split-bf16 MFMA GEMM: C = (Ah+Al)(Bh+Bl)^T + bias (drop lo*lo) ----------------
__global__ __launch_bounds__(256) void k_gemm16s(
  const bf16* __restrict__ Ah, const bf16* __restrict__ Al,
  const bf16* __restrict__ Bh, const bf16* __restrict__ Bl,
  const float* __restrict__ bias, float* __restrict__ C, int M, int K)
{
  int tid=threadIdx.x;
  int wave=tid>>6, lane=tid&63;
  int wr=wave>>1, wc=wave&1;
  int row0=blockIdx.y*64 + wr*32;
  int col0=blockIdx.x*64 + wc*32;
  int lrow = lane&15, lq = lane>>4;
  f32x4v acc[2][2] = {};
  size_t aoff = (size_t)(row0+lrow)*K + lq*8;
  size_t boff = (size_t)(col0+lrow)*K + lq*8;
  for(int k0=0;k0<K;k0+=32){
    bf16x8v ah0=*(const bf16x8v*)(Ah+aoff+k0), ah1=*(const bf16x8v*)(Ah+aoff+(size_t)16*K+k0);
    bf16x8v al0=*(const bf16x8v*)(Al+aoff+k0), al1=*(const bf16x8v*)(Al+aoff+(size_t)16*K+k0);
    bf16x8v bh0=*(const bf16x8v*)(Bh+boff+k0), bh1=*(const bf16x8v*)(Bh+boff+(size_t)16*K+k0);
    bf16x8v bl0=*(const bf16x8v*)(Bl+boff+k0), bl1=*(const bf16x8v*)(Bl+boff+(size_t)16*K+k0);
    acc[0][0]=__builtin_amdgcn_mfma_f32_16x16x32_bf16(ah0,bh0,acc[0][0],0,0,0);
    acc[0][1]=__builtin_amdgcn_mfma_f32_16x16x32_bf16(ah0,bh1,acc[0][1],0,0,0);
    acc[1][0]=__builtin_amdgcn_mfma_f32_16x16x32_bf16(ah1,bh0,acc[1][0],0,0,0);
    acc[1][1]=__builtin_amdgcn_mfma_f32_16x16x32_bf16(ah1,bh1,acc[1][1],0,0,0);
    acc[0][0]=__builtin_amdgcn_mfma_f32_16x16x32_bf16(ah0,bl0,acc[0][0],0,0,0);
    acc[0][1]=__builtin_amdgcn_mfma_f32_16x16x32_bf16(ah0,bl1,acc[0][1],0,0,0);
    acc[1][0]=__builtin_amdgcn_mfma_f32_16x16x32_bf16(ah1,bl0,acc[1][0],0,0,0);
    acc[1][1]=__builtin_amdgcn_mfma_f32_16x16x32_bf16(ah1,bl1,acc[1][1],0,0,0);
    acc[0][0]=__builtin_amdgcn_mfma_f32_16x16x32_bf16(al0,bh0,acc[0][0],0,0,0);
    acc[0][1]=__builtin_amdgcn_mfma_f32_16x16x32_bf16(al0,bh1,acc[0][1],0,0,0);
    acc[1][0]=__builtin_amdgcn_mfma_f32_16x16x32_bf16(al1,bh0,acc[1][0],0,0,0);
    acc[1][1]=__builtin_amdgcn_mfma_f32_16x16x32_bf16(al1,bh1,acc[1][1],0,0,0);
  }
  #pragma unroll
  for(int mi=0;mi<2;mi++){
    #pragma unroll
    for(int ni=0;ni<2;ni++){
      #pragma unroll
      for(int r=0;r<4;r++){
        int row=row0+mi*16+lq*4+r;
        int col=col0+ni*16+lrow;
        C[(size_t)row*M+col]=acc[mi][ni][r] + bias[col];
      }
    }
  }
}

// ---------------- bf16 MFMA GEMM (+ optional residual) ----------------
__global__ __launch_bounds__(256) void k_gemm16(
  const bf16* __restrict__ A, const bf16* __restrict__ Bw,
  const float* __restrict__ bias, const float* __restrict__ resid,
  float* __restrict__ C, bf16* __restrict__ C16,
  int M, int K, int relu)
{
  int tid=threadIdx.x;
  int wave=tid>>6, lane=tid&63;
  int wr=wave>>1, wc=wave&1;
  int row0=blockIdx.y*64 + wr*32;
  int col0=blockIdx.x*64 + wc*32;
  int lrow = lane&15, lq = lane>>4;
  f32x4v acc[2][2] = {};
  const bf16* Abase = A  + (size_t)(row0+lrow)*K + lq*8;
  const bf16* Bbase = Bw + (size_t)(col0+lrow)*K + lq*8;
  for(int k0=0;k0<K;k0+=32){
    bf16x8v a0 = *(const bf16x8v*)(Abase + k0);
    bf16x8v a1 = *(const bf16x8v*)(Abase + (size_t)16*K + k0);
    bf16x8v b0 = *(const bf16x8v*)(Bbase + k0);
    bf16x8v b1 = *(const bf16x8v*)(Bbase + (size_t)16*K + k0);
    acc[0][0]=__builtin_amdgcn_mfma_f32_16x16x32_bf16(a0,b0,acc[0][0],0,0,0);
    acc[0][1]=__builtin_amdgcn_mfma_f32_16x16x32_bf16(a0,b1,acc[0][1],0,0,0);
    acc[1][0]=__builtin_amdgcn_mfma_f32_16x16x32_bf16(a1,b0,acc[1][0],0,0,0);
    acc[1][1]=__builtin_amdgcn_mfma_f32_16x16x32_bf16(a1,b1,acc[1][1],0,0,0);
  }
  #pragma unroll
  for(int mi=0;mi<2;mi++){
    #pragma unroll
    for(int ni=0;ni<2;ni++){
      #pragma unroll
      for(int r=0;r<4;r++){
        int row=row0+mi*16+lq*4+r;       // C/D: col=lane&15, row=(lane>>4)*4+reg  [m89]
        int col=col0+ni*16+lrow;
        float v=acc[mi][ni][r] + (bias? bias[col]:0.f);
        if(relu) v=fmaxf(v,0.f);
        if(resid) v += resid[(size_t)row*M+col];
        if(C)   C[(size_t)row*M+col]=v;
        if(C16) C16[(size_t)row*M+col]=__float2bfloat16(v);
      }
    }
  }
}

// ---------------- fused ffn-up GEMM + relu(gate)*up -> bf16 ----------------
__global__ __launch_bounds__(256) void k_gemm16f(
  const bf16* __restrict__ A, const bf16* __restrict__ Bw,
  const float* __restrict__ bias, bf16* __restrict__ out, int K)
{
  int tid=threadIdx.x;
  int wave=tid>>6, lane=tid&63;
  int wr=wave>>1, wc=wave&1;
  int row0=blockIdx.y*64 + wr*32;
  int col0=blockIdx.x*64 + wc*32;
  int lrow = lane&15, lq = lane>>4;
  f32x4v acc[2][2] = {};
  const bf16* Abase = A  + (size_t)(row0+lrow)*K + lq*8;
  const bf16* Bbase = Bw + (size_t)(col0+lrow)*K + lq*8;
  for(int k0=0;k0<K;k0+=32){
    bf16x8v a0 = *(const bf16x8v*)(Abase + k0);
    bf16x8v a1 = *(const bf16x8v*)(Abase + (size_t)16*K + k0);
    bf16x8v b0 = *(const bf16x8v*)(Bbase + k0);
    bf16x8v b1 = *(const bf16x8v*)(Bbase + (size_t)16*K + k0);
    acc[0][0]=__builtin_amdgcn_mfma_f32_16x16x32_bf16(a0,b0,acc[0][0],0,0,0);
    acc[0][1]=__builtin_amdgcn_mfma_f32_16x16x32_bf16(a0,b1,acc[0][1],0,0,0);
    acc[1][0]=__builtin_amdgcn_mfma_f32_16x16x32_bf16(a1,b0,acc[1][0],0,0,0);
    acc[1][1]=__builtin_amdgcn_mfma_f32_16x16x32_bf16(a1,b1,acc[1][1],0,0,0);
  }
  #pragma unroll
  for(int mi=0;mi<2;mi++){
    #pragma unroll
    for(int ni=0;ni<2;ni++){
      #pragma unroll
      for(int r=0;r<4;r++){
        int row=row0+mi*16+lq*4+r;
        int col=col0+ni*16+lrow;
        float v=acc[mi][ni][r] + bias[(col>>1) + (col&1)*F_];
        float o = __shfl_xor(v, 1, 64);          // partner: same row, col^1
        if(!(lrow&1)){
          out[(size_t)row*F_ + (col>>1)] = __float2bfloat16(fmaxf(v,0.f)*o);
        }
      }
    }
  }
}

// ---------------- causal depthwise conv K=4 + silu (S-block, 256-wide) ----------------
__global__ __launch_bounds__(256) void k_conv_silu(
  const float* __restrict__ in, int ild, const float* __restrict__ w, const float* __restrict__ bws,
  float* __restrict__ out, int old_, int C)
{
  int i = blockIdx.x*256 + threadIdx.x;
  int r = i / C, c = i % C;
  if (r >= NP_) return;
  float acc = 0.f;
  if (r < NROW) {
    int b=r/S_, s=r%S_;
    acc = bws[c];
    #pragma unroll
    for(int j=0;j<4;j++){
      int ss=s-3+j;
      if(ss>=0) acc += w[c*4+j] * in[(size_t)(b*S_+ss)*ild + c];
    }
    acc = silu_(acc);
  }
  out[(size_t)r*old_ + c] = acc;
}

// ---------------- MEGA: conv(512)+silu -> headwise q,k,v (split bf16) -> ig/fg gates ------------
__global__ __launch_bounds__(256) void k_mega(
  const float* __restrict__ A,
  const float* __restrict__ cw, const float* __restrict__ cb,
  const float* __restrict__ wq, const float* __restrict__ wk, const float* __restrict__ wv,
  const float* __restrict__ wig, const float* __restrict__ big,
  const float* __restrict__ wfg, const float* __restrict__ bfg,
  float* __restrict__ xcout,
  bf16* __restrict__ qhi, bf16* __restrict__ qlo,
  bf16* __restrict__ khi, bf16* __restrict__ klo,
  bf16* __restrict__ vhi, bf16* __restrict__ vlo,
  float* __restrict__ igb, float* __restrict__ fgb)
{
  __shared__ float xcs[512];
  __shared__ float xms[512];
  __shared__ float qs[512], ks[512], vs[512];
  int r = blockIdx.x;
  int tid = threadIdx.x;
  if (r >= NROW){
    bf16 z = __float2bfloat16(0.f);
    size_t o = (size_t)r*512 + tid*2;
    qhi[o]=z; qhi[o+1]=z; qlo[o]=z; qlo[o+1]=z;
    khi[o]=z; khi[o+1]=z; klo[o]=z; klo[o+1]=z;
    vhi[o]=z; vhi[o+1]=z; vlo[o]=z; vlo[o+1]=z;
    return;
  }
  int b=r/S_, s=r%S_;
  const float* arow = A + (size_t)r*1024;
  for (int c=tid; c<512; c+=256){
    float acc = cb[c];
    #pragma unroll
    for(int j=0;j<4;j++){
      int ss=s-3+j;
      if(ss>=0) acc += cw[c*4+j]*A[((size_t)(b*S_+ss))*1024 + c];
    }
    acc = silu_(acc);
    xcs[c]=acc;
    xcout[(size_t)r*512+c]=acc;
    xms[c]=arow[c];
  }
  __syncthreads();
  for (int c=tid; c<512; c+=256){
    int n=c>>2, o=c&3;
    float aq=0.f, ak=0.f, av=0.f;
    #pragma unroll
    for(int d=0;d<4;d++){
      aq += xcs[n*4+d]*wq[(n*4+o)*4+d];
      ak += xcs[n*4+d]*wk[(n*4+o)*4+d];
      av += xms[n*4+d]*wv[(n*4+o)*4+d];
    }
    qs[c]=aq; ks[c]=ak; vs[c]=av;
    size_t oi=(size_t)r*512+c;
    bf16 qh=__float2bfloat16(aq); qhi[oi]=qh; qlo[oi]=__float2bfloat16(aq-__bfloat162float(qh));
    bf16 kh=__float2bfloat16(ak); khi[oi]=kh; klo[oi]=__float2bfloat16(ak-__bfloat162float(kh));
    bf16 vh=__float2bfloat16(av); vhi[oi]=vh; vlo[oi]=__float2bfloat16(av-__bfloat162float(vh));
  }
  __syncthreads();
  int h = tid>>6, lane = tid&63;
  float ai=0.f, af=0.f;
  for(int f=lane; f<1536; f+=64){
    float val = (f<512)? qs[f] : (f<1024)? ks[f-512] : vs[f-1024];
    ai += val*wig[h*1536+f];
    af += val*wfg[h*1536+f];
  }
  for(int m=32;m;m>>=1){ ai+=__shfl_xor(ai,m,64); af+=__shfl_xor(af,m,64); }
  if(lane==0){
    igb[(b*4+h)*512+s]=ai+big[h];
    fgb[(b*4+h)*512+s]=af+bfg[h];
  }
}

// ---------------- decay prep (parallel scans): one block per bh ----------------
__global__ __launch_bounds__(256) void k_decay(
  const float* __restrict__ igb, const float* __restrict__ fgb,
  float* __restrict__ cs1, float* __restrict__ g, float* __restrict__ M)
{
  int bh = blockIdx.x; int tid = threadIdx.x;
  __shared__ float buf[512];
  __shared__ float buf2[512];
  for (int s=tid; s<512; s+=256)
    buf[s] = (s<S_) ? logsig_(fgb[bh*512+s]) : 0.f;
  __syncthreads();
  for (int off=1; off<512; off<<=1){
    int s0=tid, s1=tid+256;
    float v0 = buf[s0] + ((s0>=off)? buf[s0-off] : 0.f);
    float v1 = buf[s1] + ((s1>=off)? buf[s1-off] : 0.f);
    __syncthreads();
    buf[s0]=v0; buf[s1]=v1;
    __syncthreads();
  }
  for (int s=tid; s<512; s+=256){
    float c = buf[s];
    if (s<S_){
      cs1[bh*512+s]=c;
      float gv = igb[bh*512+s]-c;
      g[bh*512+s]=gv;
      buf2[s]=gv;
    } else buf2[s] = -3.4e38f;
  }
  __syncthreads();
  for (int off=1; off<512; off<<=1){
    int s0=tid, s1=tid+256;
    float v0 = fmaxf(buf2[s0], (s0>=off)? buf2[s0-off] : -3.4e38f);
    float v1 = fmaxf(buf2[s1], (s1>=off)? buf2[s1-off] : -3.4e38f);
    __syncthreads();
    buf2[s0]=v0; buf2[s1]=v1;
    __syncthreads();
  }
  for (int s=tid; s<S_; s+=256) M[bh*512+s] = buf2[s];
}

// ---------------- tiled attention: MFMA (pre-split bf16) flash-style + fused hout ----------------
#define TQ 32
#define TS 32
__global__ __launch_bounds__(256) void k_attn(
  const bf16* __restrict__ qhi, const bf16* __restrict__ qlo,
  const bf16* __restrict__ khi, const bf16* __restrict__ klo,
  const bf16* __restrict__ vhi, const bf16* __restrict__ vlo,
  const float* __restrict__ cs1, const float* __restrict__ g, const float* __restrict__ M,
  const float* __restrict__ onw, const float* __restrict__ skip,
  const float* __restrict__ xc, const float* __restrict__ zA,
  bf16* __restrict__ out16)
{
  __shared__ __align__(16) u16 vThi[128][40];
  __shared__ __align__(16) u16 vTlo[128][40];
  __shared__ __align__(16) u16 phi[32][40];
  __shared__ __align__(16) u16 plo[32][40];
  __shared__ float MtS[32], cssS[32], normS[32], muS[32], rsS[32];
  __shared__ float lsumW[2][32], sumA[2][32], sumB[2][32];

  int tq = blockIdx.x, bh = blockIdx.y;
  int b = bh>>2, h = bh&3;
  int tid = threadIdx.x;
  int wv = tid>>6;
  int tw = wv&1, sw = wv>>1;     // sw = QK s-half; doubles as PV d-half
  int l = tid&63;
  int lr = l&15, lg = l>>4;
  int t0 = tq*TQ;
  const float sc = 0.08838834764831843f;

  if (tid < 32){
    int t = t0 + tid; int tc = (t<S_)? t : (S_-1);
    MtS[tid]  = M[bh*512 + tc];
    cssS[tid] = cs1[bh*512 + tc];
  }

  bf16x8v qh[4], ql[4];
  {
    size_t qoff = ((size_t)(b*S_ + t0 + tw*16 + lr))*512 + h*128 + lg*8;
    #pragma unroll
    for(int k0=0;k0<4;k0++){
      qh[k0] = *(const bf16x8v*)(qhi + qoff + k0*32);
      ql[k0] = *(const bf16x8v*)(qlo + qoff + k0*32);
    }
  }

  f32x4v accpv[4] = {};
  float lsum[4] = {0.f,0.f,0.f,0.f};

  int t1 = min(t0+TQ, S_);
  int sp = tid>>4, dl = tid&15;   // V-transpose staging coords

  __syncthreads();

  for (int s0=0; s0<t1; s0+=TS){
    bf16x8v kh[4], kl2[4];
    {
      size_t koff = ((size_t)(b*S_ + s0 + sw*16 + lr))*512 + h*128 + lg*8;
      #pragma unroll
      for(int k0=0;k0<4;k0++){
        kh[k0]  = *(const bf16x8v*)(khi + koff + k0*32);
        kl2[k0] = *(const bf16x8v*)(klo + koff + k0*32);
      }
    }
    u16 vha[8], vhb[8], vla[8], vlb[8];
    {
      const u16* ha = (const u16*)vhi + ((size_t)(b*S_ + s0 + 2*sp))*512 + h*128 + dl;
      const u16* la = (const u16*)vlo + ((size_t)(b*S_ + s0 + 2*sp))*512 + h*128 + dl;
      #pragma unroll
      for(int j=0;j<8;j++){
        vha[j]=ha[16*j]; vhb[j]=ha[512+16*j];
        vla[j]=la[16*j]; vlb[j]=la[512+16*j];
      }
    }
    float g_s = g[bh*512 + s0 + sw*16 + lr];

    f32x4v cqk = {0.f,0.f,0.f,0.f};
    #pragma unroll
    for(int k0=0;k0<4;k0++){
      cqk = __builtin_amdgcn_mfma_f32_16x16x32_bf16(qh[k0], kh[k0],  cqk, 0,0,0);
      cqk = __builtin_amdgcn_mfma_f32_16x16x32_bf16(qh[k0], kl2[k0], cqk, 0,0,0);
      cqk = __builtin_amdgcn_mfma_f32_16x16x32_bf16(ql[k0], kh[k0],  cqk, 0,0,0);
    }

    int s_g = s0 + sw*16 + lr;
    u16 pw_h[4], pw_l[4];
    #pragma unroll
    for(int r=0;r<4;r++){
      int tl = tw*16 + lg*4 + r;
      int t_row = t0 + tl;
      float wvv = ((s_g <= t_row) && (t_row < S_)) ? cqk[r]*sc*expneg_(g_s - MtS[tl]) : 0.f;
      lsum[r] += wvv;
      bf16 hh = __float2bfloat16(wvv);
      float hf = __bfloat162float(hh);
      bf16 ll = __float2bfloat16(wvv - hf);
      __builtin_memcpy(&pw_h[r], &hh, 2);
      __builtin_memcpy(&pw_l[r], &ll, 2);
    }

    __syncthreads();

    #pragma unroll
    for(int r=0;r<4;r++){
      int tl = tw*16 + lg*4 + r;
      phi[tl][sw*16 + lr] = pw_h[r];
      plo[tl][sw*16 + lr] = pw_l[r];
    }
    {
      unsigned* vh32 = (unsigned*)&vThi[0][0];
      unsigned* vl32 = (unsigned*)&vTlo[0][0];
      #pragma unroll
      for(int j=0;j<8;j++){
        int d = dl + 16*j;
        vh32[d*20 + sp] = (unsigned)vha[j] | ((unsigned)vhb[j]<<16);
        vl32[d*20 + sp] = (unsigned)vla[j] | ((unsigned)vlb[j]<<16);
      }
    }

    __syncthreads();

    bf16x8v pah = *(const bf16x8v*)((const void*)(&phi[tw*16 + lr][0] + lg*8));
    bf16x8v pal = *(const bf16x8v*)((const void*)(&plo[tw*16 + lr][0] + lg*8));
    #pragma unroll
    for(int fd=0; fd<4; fd++){
      bf16x8v vbh = *(const bf16x8v*)((const void*)(&vThi[sw*64 + fd*16 + lr][0] + lg*8));
      bf16x8v vbl = *(const bf16x8v*)((const void*)(&vTlo[sw*64 + fd*16 + lr][0] + lg*8));
      accpv[fd] = __builtin_amdgcn_mfma_f32_16x16x32_bf16(pah, vbh, accpv[fd], 0,0,0);
      accpv[fd] = __builtin_amdgcn_mfma_f32_16x16x32_bf16(pah, vbl, accpv[fd], 0,0,0);
      accpv[fd] = __builtin_amdgcn_mfma_f32_16x16x32_bf16(pal, vbh, accpv[fd], 0,0,0);
    }
  }

  #pragma unroll
  for(int r=0;r<4;r++){
    #pragma unroll
    for(int m=1;m<16;m<<=1) lsum[r] += __shfl_xor(lsum[r], m, 16);
  }
  if (lr==0){
    #pragma unroll
    for(int r=0;r<4;r++) lsumW[sw][tw*16 + lg*4 + r] = lsum[r];
  }
  __syncthreads();
  if (tid < 32){
    float ls = lsumW[0][tid] + lsumW[1][tid];
    float maxD = cssS[tid] + MtS[tid];
    float nrm = fmaxf(fabsf(ls), expclamp_(-maxD));
    normS[tid] = rcp_(nrm + 1e-6f);
  }
  __syncthreads();

  float o_[4][4];
  float srow[4]={0.f,0.f,0.f,0.f}, sq[4]={0.f,0.f,0.f,0.f};
  #pragma unroll
  for(int r=0;r<4;r++){
    float scl = normS[tw*16 + lg*4 + r];
    #pragma unroll
    for(int fd=0;fd<4;fd++){
      float o = accpv[fd][r]*scl;
      o_[fd][r] = o;
      srow[r] += o; sq[r] += o*o;
    }
  }
  #pragma unroll
  for(int r=0;r<4;r++){
    #pragma unroll
    for(int m=1;m<16;m<<=1){ srow[r]+=__shfl_xor(srow[r],m,16); sq[r]+=__shfl_xor(sq[r],m,16); }
  }
  if (lr==0){
    #pragma unroll
    for(int r=0;r<4;r++){ sumA[sw][tw*16+lg*4+r]=srow[r]; sumB[sw][tw*16+lg*4+r]=sq[r]; }
  }
  __syncthreads();
  if (tid < 32){
    float mu = (sumA[0][tid]+sumA[1][tid])*(1.f/128.f);
    float ex2= (sumB[0][tid]+sumB[1][tid])*(1.f/128.f);
    muS[tid]=mu;
    rsS[tid]=rsqrtf(fmaxf(ex2 - mu*mu, 0.f)+EPS_);
  }
  __syncthreads();

  #pragma unroll
  for(int fd=0; fd<4; fd++){
    int d = sw*64 + fd*16 + lr;
    float ow = onw[h*128 + d];
    float sk = skip[h*128 + d];
    #pragma unroll
    for(int r=0;r<4;r++){
      int tl = tw*16 + lg*4 + r;
      int t = t0 + tl;
      if (t < S_){
        size_t row = (size_t)(b*S_+t);
        float hf = (o_[fd][r]-muS[tl])*rsS[tl]*ow;
        float xcv = xc[row*512 + h*128 + d];
        float zv  = zA[row*1024 + 512 + h*128 + d];
        out16[row*512 + h*128 + d] = __float2bfloat16((hf + sk*xcv)*silu_(zv));
      }
    }
  }
}

// ---------------- wx: tiled, transposed weights in registers (coalesced), h-tile in LDS ----------------
#define WXR 64
__global__ __launch_bounds__(256,2) void k_wx(
  const float* __restrict__ h, const float* __restrict__ hc,
  const float* __restrict__ gwT, const float* __restrict__ gb,
  float* __restrict__ wx)
{
  int rt = blockIdx.x, g = blockIdx.y;
  int tid = threadIdx.x;
  int n = tid>>6, e = tid&63;
  const float* src = (g<2)? hc : h;
  __shared__ __align__(16) float hs[WXR][260];
  float W[64];
  #pragma unroll
  for(int d=0;d<64;d++) W[d] = gwT[(size_t)(((g*4+n)*64+d))*64 + e];
  float bias = gb[(g*4+n)*64+e];
  int row0 = rt*WXR;
  for(int idx=tid; idx<WXR*64; idx+=256){
    int rr = idx>>6, cc4 = (idx&63)*4;
    *(float4*)&hs[rr][cc4] = *(const float4*)(src + (size_t)(row0+rr)*256 + cc4);
  }
  __syncthreads();
  #pragma unroll 4
  for(int rr=0; rr<WXR; ++rr){
    int r = row0+rr;
    if (r>=NROW) break;
    const float* hrow = &hs[rr][n*64];
    float a0=0,a1=0,a2=0,a3=0;
    #pragma unroll
    for(int d=0;d<64;d+=4){
      float4 hv = *(const float4*)&hrow[d];
      a0+=hv.x*W[d]; a1+=hv.y*W[d+1]; a2+=hv.z*W[d+2]; a3+=hv.w*W[d+3];
    }
    int b=r/S_, s=r%S_;
    wx[(((size_t)(b*4+n)*512 + s)*256) + e*4 + g] = bias + ((a0+a1)+(a2+a3));
  }
}

// ---------------- sLSTM scan: 4 waves per chain, LDS y-exchange, exp-domain cell ----------------
__global__ __launch_bounds__(256,1) void k_scan(
  const float* __restrict__ wx, const bf16* __restrict__ wf, float* __restrict__ y_out)
{
  int bn = blockIdx.x; int b = bn>>2, n = bn&3;
  int tid = threadIdx.x;
  int w = tid>>6;                  // wave id = e-block
  int l = tid&63;
  int q = l>>4;
  int el = l&15;
  int e  = w*16 + el;

  __shared__ __align__(16) unsigned short ybuf[2][64];   // bf16 bits, double-buffered

  if (tid < 128) ((unsigned short*)ybuf)[tid] = 0;       // y_{-1} = 0 (both slots)
  __syncthreads();

  bf16x8v Wf2[4][2];
  #pragma unroll
  for(int g=0; g<4; ++g){
    #pragma unroll
    for(int kf=0; kf<2; ++kf){
      Wf2[g][kf] = *(const bf16x8v*)(wf + ((size_t)((n*16 + (4*g+w))*2 + kf)*64 + l)*8);
    }
  }

  const float* wxBase = wx + ((size_t)bn*512)*256 + e*4;
  float* yst = y_out + (size_t)(b*S_)*256 + n*64 + e;

  float4 p0,p1,p2,p3;
  p0 = *(const float4*)(wxBase + (size_t)0*256);
  p1 = *(const float4*)(wxBase + (size_t)1*256);
  p2 = *(const float4*)(wxBase + (size_t)2*256);
  p3 = *(const float4*)(wxBase + (size_t)3*256);

  f32x4v z4 = {0.f,0.f,0.f,0.f};
  float c=0.f, nn=0.f, pm=1.f;     // pm = exp(m), m0 = 0

  for (int s=0; s<S_; ++s){
    int p = s&1;
    bf16x8v a0 = *(const bf16x8v*)&ybuf[p][16*q];
    bf16x8v a1 = *(const bf16x8v*)&ybuf[p][16*q+8];

    f32x4v acc0,acc1,acc2,acc3, accb0,accb1,accb2,accb3;
    acc0  = __builtin_amdgcn_mfma_f32_16x16x32_bf16(a0, Wf2[0][0], z4, 0,0,0);
    acc1  = __builtin_amdgcn_mfma_f32_16x16x32_bf16(a0, Wf2[1][0], z4, 0,0,0);
    acc2  = __builtin_amdgcn_mfma_f32_16x16x32_bf16(a0, Wf2[2][0], z4, 0,0,0);
    acc3  = __builtin_amdgcn_mfma_f32_16x16x32_bf16(a0, Wf2[3][0], z4, 0,0,0);
    accb0 = __builtin_amdgcn_mfma_f32_16x16x32_bf16(a1, Wf2[0][1], z4, 0,0,0);
    accb1 = __builtin_amdgcn_mfma_f32_16x16x32_bf16(a1, Wf2[1][1], z4, 0,0,0);
    accb2 = __builtin_amdgcn_mfma_f32_16x16x32_bf16(a1, Wf2[2][1], z4, 0,0,0);
    accb3 = __builtin_amdgcn_mfma_f32_16x16x32_bf16(a1, Wf2[3][1], z4, 0,0,0);

    float4 wg = p0; p0=p1; p1=p2; p2=p3;
    { int sp = s+4; if (sp>510) sp=510;
      p3 = *(const float4*)(wxBase + (size_t)sp*256); }

    float iraw=acc0[0]+accb0[0]+wg.x, fraw=acc1[0]+accb1[0]+wg.y;
    float zraw=acc2[0]+accb2[0]+wg.z, oraw=acc3[0]+accb3[0]+wg.w;

    float pe  = __expf(fminf(iraw, 80.f));
    float ef  = __expf(-fraw);
    float e2z = __expf(2.f*zraw);
    float eo  = __expf(-oraw);
    float sf  = rcp_(1.f+ef);
    float ps  = pm*sf;
    float pn  = fmaxf(fmaxf(pe, ps), 1e-30f);
    float rpn = rcp_(pn);
    float fg  = ps*rpn;
    float ig  = pe*rpn;
    float th  = 1.f - 2.f*rcp_(e2z+1.f);
    c  = fg*c + ig*th;
    nn = fmaxf(fg*nn + ig, 1e-30f);
    float y = rcp_(1.f+eo) * c * rcp_(nn);
    pm = pn;

    bf16 hb = __float2bfloat16(y);
    unsigned short hbits; __builtin_memcpy(&hbits,&hb,2);
    if (l < 16){
      ybuf[p^1][e] = hbits;
      yst[(size_t)s*256] = y;
    }
    asm volatile("s_waitcnt lgkmcnt(0)" ::: "memory");
    __builtin_amdgcn_s_barrier();
    asm volatile("" ::: "memory");
    __builtin_amdgcn_sched_barrier(0);
  }
}

// ---------------- yn-add + fused LN2 -> bf16 (shfl reductions) ----------------
__global__ __launch_bounds__(256) void k_ynadd_ln2(
  const float* __restrict__ y, const float* __restrict__ gn,
  float* __restrict__ x, const float* __restrict__ ln2w, bf16* __restrict__ h16)
{
  __shared__ float pA[4], pB[4];
  int r=blockIdx.x, t=threadIdx.x;
  float xv = x[(size_t)r*256+t];
  if (r < NROW){
    float v=y[(size_t)r*256+t];
    float s=v;
    for(int m=32;m;m>>=1) s+=__shfl_xor(s,m,64);
    float mu=s*(1.f/64.f);
    float d=v-mu;
    float q=d*d;
    for(int m=32;m;m>>=1) q+=__shfl_xor(q,m,64);
    float var=q*(1.f/64.f);
    xv += d*rsqrtf(var+EPS_)*gn[t];
    x[(size_t)r*256+t]=xv;
  }
  float s2 = xv;
  for(int m=32;m;m>>=1) s2 += __shfl_xor(s2,m,64);
  if((t&63)==0) pA[t>>6]=s2;
  __syncthreads();
  float mu2=(pA[0]+pA[1]+pA[2]+pA[3])*(1.f/E_);
  float dd=xv-mu2;
  float q2=dd*dd;
  for(int m=32;m;m>>=1) q2 += __shfl_xor(q2,m,64);
  if((t&63)==0) pB[t>>6]=q2;
  __syncthreads();
  float var2=(pB[0]+pB[1]+pB[2]+pB[3])*(1.f/E_);
  h16[(size_t)r*256+t]=__float2bfloat16(dd*rsqrtf(var2+EPS_)*ln2w[t]);
}

// ---------------- fused postnorm-LN + cq build -> bf16 (shfl reductions) ----------------
__global__ __launch_bounds__(256) void k_cq_ln(
  const float* __restrict__ x, const float* __restrict__ pw,
  const float* __restrict__ qe, const float* __restrict__ pide, const int* __restrict__ tgt,
  bf16* __restrict__ cq)
{
  __shared__ float pA[4], pB[4];
  int r=blockIdx.x, t=threadIdx.x;
  float v = x[(size_t)r*256+t];
  float s_=v;
  for(int m=32;m;m>>=1) s_ += __shfl_xor(s_,m,64);
  if((t&63)==0) pA[t>>6]=s_;
  __syncthreads();
  float mu=(pA[0]+pA[1]+pA[2]+pA[3])*(1.f/E_);
  float d=v-mu;
  float q_=d*d;
  for(int m=32;m;m>>=1) q_ += __shfl_xor(q_,m,64);
  if((t&63)==0) pB[t>>6]=q_;
  __syncthreads();
  float var=(pB[0]+pB[1]+pB[2]+pB[3])*(1.f/E_);
  float dv = d*rsqrtf(var+EPS_)*pw[t];
  float pe=pide[r]; int tg=tgt[r];
  size_t base=(size_t)r*1024;
  cq[base+t]=__float2bfloat16(dv-pe);
  cq[base+256+t]=__float2bfloat16(qe[(size_t)r*256+t]);
  cq[base+512+t]=__float2bfloat16((tg==1)? dv:0.f);
  cq[base+768+t]=__float2bfloat16((tg==0)? dv:0.f);
}

// ---------------- final: selected logit + sigmoid (shfl reduction) ----------------
__global__ __launch_bounds__(256) void k_final(
  const float* __restrict__ o2, const float* __restrict__ w3, const float* __restrict__ b3,
  const int* __restrict__ qsh, float* __restrict__ out)
{
  __shared__ float pA[4];
  int r=blockIdx.x, t=threadIdx.x;
  int qi=qsh[r];
  float p=o2[(size_t)r*256+t]*w3[(size_t)qi*256+t];
  for(int m=32;m;m>>=1) p += __shfl_xor(p,m,64);
  if((t&63)==0) pA[t>>6]=p;
  __syncthreads();
  if(t==0) out[r]=sig_(pA[0]+pA[1]+pA[2]+pA[3]+b3[qi]);
}

// ---------------- launch ----------------
extern "C" void kernel_launch(void* const* d_in, const int* in_sizes, int n_in,
                              void* d_out, int out_size, void* d_ws, size_t ws_size,
                              hipStream_t stream) {
  const int* questions = (const int*)d_in[0];
  const int* responses = (const int*)d_in[1];
  const int* skills    = (const int*)d_in[2];
  const float* q_embed       = (const float*)d_in[4];
  const float* qa_embed      = (const float*)d_in[5];
  const float* q_embed_diff  = (const float*)d_in[6];
  const float* qa_embed_diff = (const float*)d_in[7];
  const float* difficult_param=(const float*)d_in[8];
  const float* ln0_w   = (const float*)d_in[9];
  const float* m_up_w  = (const float*)d_in[10];
  const float* m_up_b  = (const float*)d_in[11];
  const float* m_conv_w= (const float*)d_in[12];
  const float* m_conv_b= (const float*)d_in[13];
  const float* m_q_w   = (const float*)d_in[14];
  const float* m_k_w   = (const float*)d_in[15];
  const float* m_v_w   = (const float*)d_in[16];
  const float* m_ig_w  = (const float*)d_in[17];
  const float* m_ig_b  = (const float*)d_in[18];
  const float* m_fg_w  = (const float*)d_in[19];
  const float* m_fg_b  = (const float*)d_in[20];
  const float* m_outnorm_w=(const float*)d_in[21];
  const float* m_skip  = (const float*)d_in[22];
  const float* m_down_w= (const float*)d_in[23];
  const float* m_down_b= (const float*)d_in[24];
  const float* ln1_w   = (const float*)d_in[25];
  const float* s_conv_w= (const float*)d_in[26];
  const float* s_conv_b= (const float*)d_in[27];
  const float* s_gate_w= (const float*)d_in[28];
  const float* s_rec_w = (const float*)d_in[29];
  const float* s_bias  = (const float*)d_in[30];
  const float* s_gn_w  = (const float*)d_in[31];
  const float* ln2_w   = (const float*)d_in[32];
  const float* ffn_up_w= (const float*)d_in[33];
  const float* ffn_up_b= (const float*)d_in[34];
  const float* ffn_down_w=(const float*)d_in[35];
  const float* ffn_down_b=(const float*)d_in[36];
  const float* postnorm_w=(const float*)d_in[37];
  const float* out_w1  = (const float*)d_in[38];
  const float* out_b1  = (const float*)d_in[39];
  const float* out_w2  = (const float*)d_in[40];
  const float* out_b2  = (const float*)d_in[41];
  const float* out_w3  = (const float*)d_in[42];
  const float* out_b3  = (const float*)d_in[43];

  float* ws = (float*)d_ws;
  const size_t R = (size_t)NP_*256;
  float* x    = ws;
  float* qe   = ws + R;
  float* h    = ws + 2*R;        // holds hout16 during attn; later ln1 output
  float* t256 = ws + 3*R;        // early: split-bf16 LN0 output (h_hi/h_lo); late: out_w2 result
  float* A    = ws + 4*R;        // NP x 1024 ; also scan-layout wx
  float* Bb   = ws + 8*R;        // NP x 512 (xc)
  float* Cb   = ws + 10*R;       // NP x 512  (q hi/lo; later b16)
  float* Db   = ws + 12*R;       // NP x 512  (k hi/lo; later ffg16)
  float* Eb   = ws + 14*R;       // NP x 512  (v hi/lo; later cq16)
  float* pide = ws + 16*R;
  int*   tgt  = (int*)(ws + 16*R + NP_);
  int*   qsh  = (int*)(ws + 16*R + 2*NP_);
  float* igb  = ws + 16*R + 3*NP_;
  float* fgb  = igb + 64*512;
  float* cs1  = fgb + 64*512;
  float* gdec = cs1 + 64*512;
  float* Mrun = gdec + 64*512;
  bf16* wpool = (bf16*)(Mrun + 64*512);
  bf16* m_down_w16  = wpool;
  bf16* ffn_up_w16  = m_down_w16 + 256*512;
  bf16* ffn_down_w16= ffn_up_w16 + 768*256;
  bf16* out_w1_16   = ffn_down_w16 + 256*384;
  bf16* out_w2_16   = out_w1_16 + 512*1024;
  bf16* h16         = out_w2_16 + 256*512;
  bf16* m_up_whi    = h16 + (size_t)NP_*256;     // 1024*256
  bf16* m_up_wlo    = m_up_whi + 1024*256;       // 1024*256
  float* gwT        = (float*)(m_up_wlo + 1024*256);  // 16*64*64 floats
  bf16* wfrag       = (bf16*)(gwT + 16*64*64);   // 65536 bf16: MFMA B-frags of s_rec_w
  bf16* q_hi = (bf16*)Cb;  bf16* q_lo = q_hi + (size_t)NP_*512;
  bf16* k_hi = (bf16*)Db;  bf16* k_lo = k_hi + (size_t)NP_*512;
  bf16* v_hi = (bf16*)Eb;  bf16* v_lo = v_hi + (size_t)NP_*512;
  bf16* hout16 = (bf16*)h;                       // NP*512 bf16
  bf16* ffg16  = (bf16*)Db;
  bf16* cq16   = (bf16*)Eb;
  bf16* b16    = (bf16*)Cb;
  bf16* h_hi   = (bf16*)t256;                    // NP*256
  bf16* h_lo   = h_hi + (size_t)NP_*256;         // NP*256

  // ---- one-shot weight prep ----
  k_prep<<<5760,256,0,stream>>>(
      m_down_w, m_down_w16, ffn_up_w, ffn_up_w16, ffn_down_w, ffn_down_w16,
      out_w1, out_w1_16, out_w2, out_w2_16, m_up_w, m_up_whi, m_up_wlo,
      s_gate_w, gwT, s_rec_w, wfrag);

  // ---- embeddings (+LN0 -> split bf16) ----
  k_embed<<<NP_,256,0,stream>>>(questions,responses,skills,q_embed,qa_embed,
      q_embed_diff,qa_embed_diff,difficult_param, ln0_w, x,qe, h_hi,h_lo, pide,tgt,qsh);
  // ---- block M ----
  k_gemm16s<<<dim3(1024/64,NP_/64),256,0,stream>>>(h_hi,h_lo, m_up_whi,m_up_wlo, m_up_b, A, 1024,256);
  k_mega<<<NP_,256,0,stream>>>(A, m_conv_w,m_conv_b, m_q_w,m_k_w,m_v_w,
      m_ig_w,m_ig_b,m_fg_w,m_fg_b, Bb, q_hi,q_lo, k_hi,k_lo, v_hi,v_lo, igb,fgb);
  k_decay<<<64,256,0,stream>>>(igb,fgb, cs1,gdec,Mrun);
  hipMemsetAsync(hout16 + (size_t)NROW*512, 0, (size_t)(NP_-NROW)*512*sizeof(bf16), stream);
  k_attn<<<dim3((S_+TQ-1)/TQ, B_*NH_),256,0,stream>>>(q_hi,q_lo, k_hi,k_lo, v_hi,v_lo,
      cs1,gdec,Mrun, m_outnorm_w, m_skip, Bb, A, hout16);
  k_gemm16<<<dim3(256/64,NP_/64),256,0,stream>>>(hout16, m_down_w16, m_down_b, x, x, (bf16*)nullptr, 256,512,0);
  // ---- block S ----
  k_ln<<<NP_,256,0,stream>>>(x, ln1_w, h);
  k_conv_silu<<<(NP_*256)/256,256,0,stream>>>(h,256, s_conv_w,s_conv_b, Bb,256,256);
  k_wx<<<dim3(128,4),256,0,stream>>>(h, Bb, gwT, s_bias, A);
  k_scan<<<64,256,0,stream>>>(A, wfrag, Cb);
  k_ynadd_ln2<<<NP_,256,0,stream>>>(Cb, s_gn_w, x, ln2_w, h16);
  // ---- FFN (fused up-proj + relu-mul) ----
  k_gemm16f<<<dim3(768/64,NP_/64),256,0,stream>>>(h16, ffn_up_w16, ffn_up_b, ffg16, 256);
  k_gemm16<<<dim3(256/64,NP_/64),256,0,stream>>>(ffg16, ffn_down_w16, ffn_down_b, x, x, (bf16*)nullptr, 256,384,0);
  // ---- output head ----
  k_cq_ln<<<NP_,256,0,stream>>>(x, postnorm_w, qe, pide, tgt, cq16);
  k_gemm16<<<dim3(512/64,NP_/64),256,0,stream>>>(cq16, out_w1_16, out_b1, (const float*)nullptr, (float*)nullptr, b16, 512,1024,1);
  k_gemm16<<<dim3(256/64,NP_/64),256,0,stream>>>(b16, out_w2_16, out_b2, (const float*)nullptr, t256, (bf16*)nullptr, 256,512,1);
  k_final<<<NROW,256,0,stream>>>(t256, out_w3, out_b3, qsh, (float*)d_out);
}